// Round 6
// baseline (330.324 us; speedup 1.0000x reference)
//
#include <hip/hip_runtime.h>
#include <math.h>

#define N_NODES 20000
#define E_EDGES 200000
#define K1_KEEP 10000
#define K2_KEEP 5000
#define HIDC 128
#define NHEAD 4
#define FDIM 512   // NHEAD*HIDC
#define NEG 0.2f
#define BSTRIDE 64 // bucket CSR stride; P(deg>64)~e^-64 for Binom(200k,1/20k)
#define SELCAP 20  // keys/thread in select (1024*20 >= 20000)
#define MPAD 10112 // 79*128: K1 rows padded to GEMM2 tile grid

typedef _Float16 half8 __attribute__((ext_vector_type(8)));
typedef _Float16 half4 __attribute__((ext_vector_type(4)));
typedef float f32x4 __attribute__((ext_vector_type(4)));

__device__ __forceinline__ float leaky(float x){ return x > 0.f ? x : NEG * x; }
__device__ __forceinline__ float elu(float x){ return x > 0.f ? x : expm1f(x); }
// monotone float->uint key (ascending)
__device__ __forceinline__ unsigned ordkey(float f){
    unsigned u = __float_as_uint(f);
    return (u & 0x80000000u) ? ~u : (u | 0x80000000u);
}

// ---------------- GEMM1 (fp32 vector path, layer 1 only) -------------------
// 64x128 tile / 256 threads / KC=32 LDS stage. Only instantiated for the
// K=64 layer-1 GEMM. AMODE 1: full attention dots in epilogue (fp32 acc).
// r4: h output stored as fp16 (gather consumer is service-rate-bound).
template<int K, int COLB, int AMODE, bool GATHER, bool CLEAR>
__global__ __launch_bounds__(256) void gemm_tile(const float* __restrict__ A,
        const float* __restrict__ W, _Float16* __restrict__ out,
        const int* __restrict__ gidx, const float* __restrict__ gsc,
        const float* __restrict__ avS, const float* __restrict__ avD,
        float* __restrict__ asrc, float* __restrict__ adst, int n,
        int ngemm, int* __restrict__ ctmp, int cn,
        const float* __restrict__ cw, float* __restrict__ cinvn)
{
    int t = threadIdx.x;
    int bid = blockIdx.x;
    if constexpr (CLEAR){
        if (bid >= ngemm){
            __shared__ float redc[4];
            int b2 = bid - ngemm;
            int i = b2 * 256 + t;
            if (i < cn) ctmp[i] = 0;
            if (b2 == 0){
                float s = cw[t] * cw[t] + cw[t + 256] * cw[t + 256];
#pragma unroll
                for (int off = 32; off > 0; off >>= 1) s += __shfl_xor(s, off);
                if ((t & 63) == 0) redc[t >> 6] = s;
                __syncthreads();
                if (t == 0) *cinvn = rsqrtf(redc[0] + redc[1] + redc[2] + redc[3]);
            }
            return;
        }
    }
    constexpr int NR = COLB / 16;
    constexpr int WPT = COLB / 32;
    constexpr int BPR = 512 / COLB;
    __shared__ float At[32][68];
    __shared__ float Wt[32][COLB];
    int row0 = (bid / BPR) * 64;
    int col0 = (bid % BPR) * COLB;
    int tr = t >> 4;
    int tc = t & 15;
    float acc[4][NR] = {};

    int arow[2]; float asc[2];
#pragma unroll
    for (int i = 0; i < 2; ++i){
        int r = (t + i * 256) >> 3;
        int gr = row0 + r;
        arow[i] = -1; asc[i] = 1.f;
        if (gr < n){
            if (GATHER){ arow[i] = gidx[gr]; asc[i] = gsc[arow[i]]; }
            else arow[i] = gr;
        }
    }

    float4 pa[2], pw[WPT];
#pragma unroll
    for (int i = 0; i < 2; ++i){
        int kq = (t + i * 256) & 7;
        pa[i] = make_float4(0.f, 0.f, 0.f, 0.f);
        if (arow[i] >= 0){
            pa[i] = *reinterpret_cast<const float4*>(&A[(size_t)arow[i] * K + kq * 4]);
            if (GATHER){ pa[i].x *= asc[i]; pa[i].y *= asc[i]; pa[i].z *= asc[i]; pa[i].w *= asc[i]; }
        }
    }
#pragma unroll
    for (int i = 0; i < WPT; ++i){
        int s = t + i * 256; int k = s / (COLB / 4), c4 = s % (COLB / 4);
        pw[i] = *reinterpret_cast<const float4*>(&W[(size_t)k * 512 + col0 + c4 * 4]);
    }

    for (int kc = 0; kc < K; kc += 32){
#pragma unroll
        for (int i = 0; i < 2; ++i){
            int s = t + i * 256; int r = s >> 3, kq = s & 7;
            At[kq * 4 + 0][r] = pa[i].x;
            At[kq * 4 + 1][r] = pa[i].y;
            At[kq * 4 + 2][r] = pa[i].z;
            At[kq * 4 + 3][r] = pa[i].w;
        }
#pragma unroll
        for (int i = 0; i < WPT; ++i){
            int s = t + i * 256; int k = s / (COLB / 4), c4 = s % (COLB / 4);
            *reinterpret_cast<float4*>(&Wt[k][c4 * 4]) = pw[i];
        }
        __syncthreads();
        if (kc + 32 < K){
            int kn = kc + 32;
#pragma unroll
            for (int i = 0; i < 2; ++i){
                int kq = (t + i * 256) & 7;
                pa[i] = make_float4(0.f, 0.f, 0.f, 0.f);
                if (arow[i] >= 0){
                    pa[i] = *reinterpret_cast<const float4*>(&A[(size_t)arow[i] * K + kn + kq * 4]);
                    if (GATHER){ pa[i].x *= asc[i]; pa[i].y *= asc[i]; pa[i].z *= asc[i]; pa[i].w *= asc[i]; }
                }
            }
#pragma unroll
            for (int i = 0; i < WPT; ++i){
                int s = t + i * 256; int k = s / (COLB / 4), c4 = s % (COLB / 4);
                pw[i] = *reinterpret_cast<const float4*>(&W[(size_t)(kn + k) * 512 + col0 + c4 * 4]);
            }
        }
#pragma unroll 8
        for (int kk = 0; kk < 32; ++kk){
            float4 a = *reinterpret_cast<const float4*>(&At[kk][tr * 4]);
            float af[4] = {a.x, a.y, a.z, a.w};
            float wf[NR];
            {
                float4 w0 = *reinterpret_cast<const float4*>(&Wt[kk][tc * 4]);
                wf[0] = w0.x; wf[1] = w0.y; wf[2] = w0.z; wf[3] = w0.w;
                if constexpr (NR == 8){
                    float4 w1 = *reinterpret_cast<const float4*>(&Wt[kk][tc * 4 + 64]);
                    wf[4] = w1.x; wf[5] = w1.y; wf[6] = w1.z; wf[7] = w1.w;
                }
            }
#pragma unroll
            for (int r = 0; r < 4; ++r)
#pragma unroll
                for (int c = 0; c < NR; ++c) acc[r][c] += af[r] * wf[c];
        }
        __syncthreads();
    }
#pragma unroll
    for (int r = 0; r < 4; ++r){
        int gr = row0 + 4 * tr + r;
        if (gr < n){
            half4 h0, h1q;
#pragma unroll
            for (int c = 0; c < 4; ++c) h0[c] = (_Float16)acc[r][c];
            *reinterpret_cast<half4*>(&out[(size_t)gr * 512 + col0 + tc * 4]) = h0;
            if constexpr (NR == 8){
#pragma unroll
                for (int c = 0; c < 4; ++c) h1q[c] = (_Float16)acc[r][4 + c];
                *reinterpret_cast<half4*>(&out[(size_t)gr * 512 + col0 + 64 + tc * 4]) = h1q;
            }
        }
    }
    if constexpr (AMODE == 1){
        int head = col0 >> 7;
        const float* as = avS + head * HIDC;
        const float* ad = avD + head * HIDC;
#pragma unroll
        for (int r = 0; r < 4; ++r){
            float s = 0.f, d = 0.f;
#pragma unroll
            for (int c = 0; c < 4; ++c){
                s += acc[r][c] * as[4 * tc + c];
                d += acc[r][c] * ad[4 * tc + c];
                s += acc[r][4 + c] * as[64 + 4 * tc + c];
                d += acc[r][4 + c] * ad[64 + 4 * tc + c];
            }
#pragma unroll
            for (int off = 1; off < 16; off <<= 1){ s += __shfl_xor(s, off); d += __shfl_xor(d, off); }
            int gr = row0 + 4 * tr + r;
            if (tc == 0 && gr < n){ asrc[gr * 4 + head] = s; adst[gr * 4 + head] = d; }
        }
    }
}

// --------- prep: transpose + fp16x2-split W2 -> W2T planes [n][k] ----------
__global__ __launch_bounds__(256) void prep_w2(const float* __restrict__ W2,
        _Float16* __restrict__ B0, _Float16* __restrict__ B1)
{
    __shared__ float tile[32][33];
    int bn = blockIdx.x & 15, bk = blockIdx.x >> 4;
    int n0 = bn * 32, k0 = bk * 32;
    int t = threadIdx.x;
    int j = t & 31, i0 = t >> 5;           // 8 row-groups of 32 cols
#pragma unroll
    for (int ii = 0; ii < 32; ii += 8)
        tile[i0 + ii][j] = W2[(size_t)(k0 + i0 + ii) * 512 + n0 + j];
    __syncthreads();
#pragma unroll
    for (int ii = 0; ii < 32; ii += 8){
        float v = tile[j][i0 + ii];        // = W2[k0+j][n0+i0+ii]
        _Float16 h0 = (_Float16)v;
        _Float16 h1 = (_Float16)(v - (float)h0);
        size_t o = (size_t)(n0 + i0 + ii) * 512 + k0 + j;
        B0[o] = h0; B1[o] = h1;
    }
}

// --------- prep: gather+scale+fp16x2-split A -> A planes [MPAD][512] -------
__global__ __launch_bounds__(256) void prep_a(const float* __restrict__ out1,
        const int* __restrict__ oldi, const float* __restrict__ score,
        _Float16* __restrict__ A0, _Float16* __restrict__ A1)
{
    int tid = blockIdx.x * 256 + threadIdx.x;   // MPAD*64 total
    int r = tid >> 6, kq = (tid & 63) << 3;
    half8 v0 = (half8)0, v1 = (half8)0;
    if (r < K1_KEEP){
        int o = oldi[r];
        float sc = score[o];
        const float4* p = reinterpret_cast<const float4*>(&out1[(size_t)o * 512 + kq]);
        float4 x0 = p[0], x1 = p[1];
        float vals[8] = {x0.x, x0.y, x0.z, x0.w, x1.x, x1.y, x1.z, x1.w};
#pragma unroll
        for (int j = 0; j < 8; ++j){
            float v = vals[j] * sc;
            _Float16 h = (_Float16)v;
            v0[j] = h;
            v1[j] = (_Float16)(v - (float)h);
        }
    }
    *reinterpret_cast<half8*>(&A0[(size_t)r * 512 + kq]) = v0;
    *reinterpret_cast<half8*>(&A1[(size_t)r * 512 + kq]) = v1;
}

// ---------------- GEMM2: fp16x2 split MFMA, 128x128 tile -------------------
// C[10000x512] = A@W2 via 3 products A0B0+A0B1+A1B0 in fp32 MFMA acc
// (~fp32 precision). Verified r2: GEMM2 fp32->MFMA cut total 467->406us.
// r4: C stored fp16 (consumed only by gat_fused's gather).
__global__ __launch_bounds__(256, 2) void gemm2_mfma(
        const _Float16* __restrict__ A0, const _Float16* __restrict__ A1,
        const _Float16* __restrict__ B0, const _Float16* __restrict__ B1,
        const float* __restrict__ avS, const float* __restrict__ avD,
        _Float16* __restrict__ C, float* __restrict__ asrc, float* __restrict__ adst)
{
    __shared__ _Float16 smem[2][4][128][32];   // 65536 B
    int t = threadIdx.x;
    int l = t & 63, w = t >> 6;
    int wr = w >> 1, wc = w & 1;
    int bidn = blockIdx.x & 3, bidm = blockIdx.x >> 2;
    int row0 = bidm * 128, col0 = bidn * 128;

    // wave w stages plane w: 0->A0 1->A1 2->B0 3->B1
    const _Float16* plane = (w == 0) ? A0 : (w == 1) ? A1 : (w == 2) ? B0 : B1;
    int prow0 = (w < 2) ? row0 : col0;
    int mloc = l >> 2;                        // row within 16-row stripe
    int gsw = (l & 3) ^ (mloc & 3);           // inverse-swizzled src granule
    const _Float16* gbase = plane + (size_t)(prow0 + mloc) * 512 + gsw * 8;

    f32x4 acc[4][4];
#pragma unroll
    for (int m = 0; m < 4; ++m)
#pragma unroll
        for (int n = 0; n < 4; ++n) acc[m][n] = (f32x4){0.f, 0.f, 0.f, 0.f};

    auto stage = [&](int buf, int chunk){
        const _Float16* src = gbase + chunk * 32;
        char* db = (char*)&smem[buf][w][0][0];
#pragma unroll
        for (int i = 0; i < 8; ++i)
            __builtin_amdgcn_global_load_lds(
                (const __attribute__((address_space(1))) void*)(src + (size_t)i * 8192),
                (__attribute__((address_space(3))) void*)(db + i * 1024), 16, 0, 0);
    };

    // frag read: row = l&15, k-granule = (l>>4) ^ swizzle(row&3) = (l>>4)^(l&3)
    int rb = (l & 15) * 64 + (((l >> 4) ^ (l & 3)) * 16);
    const char* sb = (const char*)smem;

    stage(0, 0);
    __syncthreads();
    for (int c = 0; c < 16; ++c){
        int buf = c & 1;
        if (c < 15) stage(buf ^ 1, c + 1);
        const char* base = sb + buf * 32768;
        half8 a0[4], a1[4], b0[4], b1[4];
#pragma unroll
        for (int m = 0; m < 4; ++m){
            a0[m] = *(const half8*)(base +         wr * 4096 + m * 1024 + rb);
            a1[m] = *(const half8*)(base +  8192 + wr * 4096 + m * 1024 + rb);
            b0[m] = *(const half8*)(base + 16384 + wc * 4096 + m * 1024 + rb);
            b1[m] = *(const half8*)(base + 24576 + wc * 4096 + m * 1024 + rb);
        }
        // product-major order: each acc reused every 16 MFMAs (no RAW stall)
#pragma unroll
        for (int m = 0; m < 4; ++m)
#pragma unroll
            for (int n = 0; n < 4; ++n)
                acc[m][n] = __builtin_amdgcn_mfma_f32_16x16x32_f16(a0[m], b0[n], acc[m][n], 0, 0, 0);
#pragma unroll
        for (int m = 0; m < 4; ++m)
#pragma unroll
            for (int n = 0; n < 4; ++n)
                acc[m][n] = __builtin_amdgcn_mfma_f32_16x16x32_f16(a0[m], b1[n], acc[m][n], 0, 0, 0);
#pragma unroll
        for (int m = 0; m < 4; ++m)
#pragma unroll
            for (int n = 0; n < 4; ++n)
                acc[m][n] = __builtin_amdgcn_mfma_f32_16x16x32_f16(a1[m], b0[n], acc[m][n], 0, 0, 0);
        __syncthreads();
    }

    // epilogue: C/D frag layout col=lane&15, row=(lane>>4)*4+reg (m89)
    int head = bidn;
    const float* asv = avS + head * HIDC + wc * 64;
    const float* adv = avD + head * HIDC + wc * 64;
    int lc = l & 15, lg = l >> 4;
    int rbase = row0 + wr * 64;
    int cbase = col0 + wc * 64;
#pragma unroll
    for (int m = 0; m < 4; ++m){
#pragma unroll
        for (int q = 0; q < 4; ++q){
            int row = rbase + m * 16 + lg * 4 + q;
            bool ok = row < K1_KEEP;
            float s = 0.f, d = 0.f;
#pragma unroll
            for (int n = 0; n < 4; ++n){
                float v = acc[m][n][q];
                int cc = n * 16 + lc;
                if (ok) C[(size_t)row * 512 + cbase + cc] = (_Float16)v;
                s += v * asv[cc];
                d += v * adv[cc];
            }
#pragma unroll
            for (int off = 1; off < 16; off <<= 1){
                s += __shfl_xor(s, off);
                d += __shfl_xor(d, off);
            }
            if (ok && lc == 0){
                asrc[row * 8 + head * 2 + wc] = s;   // half-pair layout [n][4][2]
                adst[row * 8 + head * 2 + wc] = d;
            }
        }
    }
}

// bucketed CSR fill: no count/scan passes needed; tmp returns degrees.
__global__ void edge_fill(const int* __restrict__ src, const int* __restrict__ dst, int e,
                          int* __restrict__ tmp, int* __restrict__ csr){
    int i = blockIdx.x * 256 + threadIdx.x;
    if (i >= e) return;
    int d = dst[i];
    int pos = atomicAdd(&tmp[d], 1);
    if (pos < BSTRIDE) csr[d * BSTRIDE + pos] = src[i];
}

// ---- fused softmax-stats + aggregation + pool score, one wave per node -----
// r4: h rows fp16 (16B/lane/edge) — gather service-rate-bound, bytes halved.
template<bool FILTER>
__global__ __launch_bounds__(256) void gat_fused(const _Float16* __restrict__ h,
        const float* __restrict__ asrc, const float* __restrict__ adst,
        const int* __restrict__ degs, const int* __restrict__ csr,
        const int* __restrict__ oldi, const int* __restrict__ remap,
        const float* __restrict__ bias, const float* __restrict__ pw,
        const float* __restrict__ invn, float* __restrict__ out,
        float* __restrict__ score, int n)
{
    int node = blockIdx.x * 4 + (threadIdx.x >> 6);
    int lane = threadIdx.x & 63;
    if (node >= n) return;
    int od = FILTER ? oldi[node] : node;
    int deg = degs[od]; if (deg > BSTRIDE) deg = BSTRIDE;
    int e0 = od * BSTRIDE;
    int ph = lane & 3;
    int pe = lane >> 2;
    float adn, sown;
    if (FILTER){
        float2 dv = *reinterpret_cast<const float2*>(&adst[(size_t)node * 8 + ph * 2]);
        float2 sv = *reinterpret_cast<const float2*>(&asrc[(size_t)node * 8 + ph * 2]);
        adn = dv.x + dv.y; sown = sv.x + sv.y;
    } else {
        adn = adst[node * 4 + ph]; sown = asrc[node * 4 + ph];
    }
    float slog = leaky(sown + adn);
    int sreg[4];
    float mx = slog;
#pragma unroll
    for (int blk = 0; blk < 4; ++blk){
        int j = blk * 16 + pe;
        int s = -1;
        if (j < deg){
            s = csr[e0 + j];
            if (FILTER) s = remap[s];
            if (s >= 0){
                float av;
                if (FILTER){
                    float2 v = *reinterpret_cast<const float2*>(&asrc[(size_t)s * 8 + ph * 2]);
                    av = v.x + v.y;
                } else av = asrc[s * 4 + ph];
                mx = fmaxf(mx, leaky(av + adn));
            }
        }
        sreg[blk] = s;
    }
#pragma unroll
    for (int off = 4; off < 64; off <<= 1) mx = fmaxf(mx, __shfl_xor(mx, off));
    float aexp[4];
    float lsum = 0.f;
#pragma unroll
    for (int blk = 0; blk < 4; ++blk){
        float ex = 0.f;
        int s = sreg[blk];
        if (s >= 0){
            float av;
            if (FILTER){
                float2 v = *reinterpret_cast<const float2*>(&asrc[(size_t)s * 8 + ph * 2]);
                av = v.x + v.y;
            } else av = asrc[s * 4 + ph];
            ex = expf(leaky(av + adn) - mx);
        }
        aexp[blk] = ex;
        lsum += ex;
    }
#pragma unroll
    for (int off = 4; off < 64; off <<= 1) lsum += __shfl_xor(lsum, off);
    float es  = expf(slog - mx);
    float inv = 1.f / (lsum + es);

    int f0 = lane * 8;
    int hf = lane >> 4;
    float invh  = __shfl(inv, hf);       // lane hf holds head hf's stats
    float aself = __shfl(es, hf) * invh;
    float4 acc0, acc1;
    {
        half8 v = *reinterpret_cast<const half8*>(&h[(size_t)node * FDIM + f0]);
        acc0 = make_float4(aself * (float)v[0], aself * (float)v[1],
                           aself * (float)v[2], aself * (float)v[3]);
        acc1 = make_float4(aself * (float)v[4], aself * (float)v[5],
                           aself * (float)v[6], aself * (float)v[7]);
    }
#pragma unroll
    for (int blk = 0; blk < 4; ++blk){
        int base = blk * 16;
        if (base >= deg) break;
        int cnt = deg - base; if (cnt > 16) cnt = 16;
        for (int e = 0; e < cnt; ++e){
            int s = __shfl(sreg[blk], e * 4);
            if (FILTER && s < 0) continue;
            float al = __shfl(aexp[blk], e * 4 + hf) * invh;
            half8 u = *reinterpret_cast<const half8*>(&h[(size_t)s * FDIM + f0]);
            acc0.x += al * (float)u[0]; acc0.y += al * (float)u[1];
            acc0.z += al * (float)u[2]; acc0.w += al * (float)u[3];
            acc1.x += al * (float)u[4]; acc1.y += al * (float)u[5];
            acc1.z += al * (float)u[6]; acc1.w += al * (float)u[7];
        }
    }
    const float4* bp = reinterpret_cast<const float4*>(&bias[f0]);
    float4 b0 = bp[0], b1 = bp[1];
    float4 o0 = make_float4(elu(acc0.x + b0.x), elu(acc0.y + b0.y),
                            elu(acc0.z + b0.z), elu(acc0.w + b0.w));
    float4 o1 = make_float4(elu(acc1.x + b1.x), elu(acc1.y + b1.y),
                            elu(acc1.z + b1.z), elu(acc1.w + b1.w));
    float4* op = reinterpret_cast<float4*>(&out[(size_t)node * FDIM + f0]);
    op[0] = o0; op[1] = o1;
    // fused TopK pool score
    const float4* wp = reinterpret_cast<const float4*>(&pw[f0]);
    float4 w0 = wp[0], w1 = wp[1];
    float s = o0.x * w0.x + o0.y * w0.y + o0.z * w0.z + o0.w * w0.w
            + o1.x * w1.x + o1.y * w1.y + o1.z * w1.z + o1.w * w1.w;
#pragma unroll
    for (int off = 32; off > 0; off >>= 1) s += __shfl_xor(s, off);
    if (lane == 0) score[node] = tanhf(s * (*invn));
}

// ---- exact top-k select (4x 8-bit radix) + compact, single block -----------
// r5: threshold scan parallelized (suffix-scan over 256 buckets); verified
// r5 bench: select_compact left the top-5 (was 50-60us x2).
__global__ __launch_bounds__(1024) void select_compact(const float* __restrict__ score,
        int n, int k, int* __restrict__ remap, int* __restrict__ oldidx,
        float* __restrict__ gsum, int* __restrict__ done,
        const float* __restrict__ w, float* __restrict__ invn)
{
    __shared__ unsigned hist[16][256];
    __shared__ unsigned wtot[4];
    __shared__ unsigned s_prefix, s_rem, l_tie, l_keep;
    __shared__ float red2[16];
    int t = threadIdx.x;
    int wv = t >> 6;
    unsigned keys[SELCAP];
#pragma unroll
    for (int j = 0; j < SELCAP; ++j){
        int i = t + j * 1024;
        keys[j] = (i < n) ? ordkey(score[i]) : 0u;
    }
    if (t == 0){ s_prefix = 0u; s_rem = (unsigned)k; l_tie = 0u; l_keep = 0u; }
    for (int i = t; i < 16 * 256; i += 1024) ((unsigned*)hist)[i] = 0u;
    __syncthreads();
    for (int pass = 3; pass >= 0; --pass){
        unsigned shift = (unsigned)pass * 8u;
        unsigned pmask = (pass == 3) ? 0u : (0xFFFFFFFFu << (shift + 8u));
        unsigned pref = s_prefix;
        unsigned remv = s_rem;           // all threads read before any write
#pragma unroll
        for (int j = 0; j < SELCAP; ++j){
            int i = t + j * 1024;
            if (i < n && (keys[j] & pmask) == pref)
                atomicAdd(&hist[wv][(keys[j] >> shift) & 255u], 1u);
        }
        __syncthreads();
        unsigned c = 0, v = 0;
        if (t < 256){
            unsigned a = 0;
#pragma unroll
            for (int wq = 0; wq < 16; ++wq) a += hist[wq][t];
            c = a; v = a;
            // inclusive suffix scan within this wave's 64-bucket chunk
#pragma unroll
            for (int off = 1; off < 64; off <<= 1){
                unsigned o = __shfl_down(v, off);
                if ((t & 63) + off < 64) v += o;
            }
            if ((t & 63) == 0) wtot[t >> 6] = v;   // chunk total (lane 0 = full suffix of chunk)
        }
        __syncthreads();
        if (t < 256){
#pragma unroll
            for (int q = 0; q < 4; ++q)
                if (q > (t >> 6)) v += wtot[q];    // add totals of higher chunks
            unsigned nxt = v - c;                   // suffix(t+1)
            if (v >= remv && nxt < remv){           // unique: suffix monotone
                s_prefix = pref | ((unsigned)t << shift);
                s_rem = remv - nxt;
            }
        }
        __syncthreads();
        if (pass > 0){
            for (int i = t; i < 16 * 256; i += 1024) ((unsigned*)hist)[i] = 0u;
            __syncthreads();
        }
    }
    unsigned T = s_prefix, ties = s_rem;
#pragma unroll
    for (int j = 0; j < SELCAP; ++j){
        int i = t + j * 1024;
        if (i >= n) continue;
        unsigned key = keys[j];
        int keep = 0;
        if (key > T) keep = 1;
        else if (key == T){
            unsigned tk = atomicAdd(&l_tie, 1u);
            if (tk < ties) keep = 1;
        }
        if (keep){
            int pos = (int)atomicAdd(&l_keep, 1u);
            remap[i] = pos;
            oldidx[pos] = i;
        } else remap[i] = -1;
    }
    if (gsum){
        if (t < 512) gsum[t] = 0.f;
        if (t == 0) *done = 0;
        float s = (t < 512) ? w[t] * w[t] : 0.f;
#pragma unroll
        for (int off = 32; off > 0; off >>= 1) s += __shfl_xor(s, off);
        if ((t & 63) == 0) red2[wv] = s;
        __syncthreads();
        if (t == 0){
            float a = 0.f;
            for (int i = 0; i < 16; ++i) a += red2[i];
            *invn = rsqrtf(a);
        }
    }
}

// --------- readout: mean-pool reduce + final 512x10 GEMM (last block) -------
// r6: grid 64->512 + 4-wide unrolled gather. r5 counters (48us, VALU 0.25%,
// HBM 1.5%, occ 4.7%) = serialized dependent chain: 78 iters x ~1500cy of
// oldidx->row load per block. Now ~10 rows/block as 4 independent loads per
// step; per-block chain ~3 steps. 512 atomics/feature address is cheap.
#define FR_GRID 512
__global__ __launch_bounds__(512) void final_reduce(const float* __restrict__ x,
        const int* __restrict__ oldidx, const float* __restrict__ score, int k,
        float* __restrict__ gsum, int* __restrict__ done,
        const float* __restrict__ Wl, const float* __restrict__ bl,
        float* __restrict__ out)
{
    __shared__ float gsh[512];
    __shared__ int last;
    int t = threadIdx.x; // 512
    int g = gridDim.x;
    float a = 0.f;
    for (int j = blockIdx.x; j < k; j += 4 * g){
        int j1 = j + g, j2 = j + 2 * g, j3 = j + 3 * g;
        int o0 = oldidx[j];
        int o1 = j1 < k ? oldidx[j1] : o0;
        int o2 = j2 < k ? oldidx[j2] : o0;
        int o3 = j3 < k ? oldidx[j3] : o0;
        float s0 = score[o0];
        float s1 = j1 < k ? score[o1] : 0.f;
        float s2 = j2 < k ? score[o2] : 0.f;
        float s3 = j3 < k ? score[o3] : 0.f;
        float v0 = x[(size_t)o0 * FDIM + t];
        float v1 = x[(size_t)o1 * FDIM + t];
        float v2 = x[(size_t)o2 * FDIM + t];
        float v3 = x[(size_t)o3 * FDIM + t];
        a += v0 * s0 + v1 * s1 + v2 * s2 + v3 * s3;
    }
    atomicAdd(&gsum[t], a);
    __threadfence();
    if (t == 0) last = (atomicAdd(done, 1) == (int)gridDim.x - 1);
    __syncthreads();
    if (!last) return;
    gsh[t] = atomicAdd(&gsum[t], 0.f);
    __syncthreads();
    int wv = t >> 6, lane = t & 63;
    for (int w = wv; w < 10; w += 8){
        float s = 0.f;
        for (int f = lane; f < FDIM; f += 64) s += gsh[f] * Wl[f * 10 + w];
#pragma unroll
        for (int off = 32; off > 0; off >>= 1) s += __shfl_xor(s, off);
        if (lane == 0) out[w] = s * (1.0f / K2_KEEP) + bl[w];
    }
}

extern "C" void kernel_launch(void* const* d_in, const int* in_sizes, int n_in,
                              void* d_out, int out_size, void* d_ws, size_t ws_size,
                              hipStream_t stream)
{
    (void)in_sizes; (void)n_in; (void)out_size; (void)ws_size;
    const float* x   = (const float*)d_in[0];
    const int*   ei  = (const int*)  d_in[1];
    const float* W1  = (const float*)d_in[3];
    const float* as1 = (const float*)d_in[4];
    const float* ad1 = (const float*)d_in[5];
    const float* b1  = (const float*)d_in[6];
    const float* pw1 = (const float*)d_in[7];
    const float* W2  = (const float*)d_in[8];
    const float* as2 = (const float*)d_in[9];
    const float* ad2 = (const float*)d_in[10];
    const float* b2  = (const float*)d_in[11];
    const float* pw2 = (const float*)d_in[12];
    const float* Wl  = (const float*)d_in[13];
    const float* bl  = (const float*)d_in[14];
    const int* src1 = ei;
    const int* dst1 = ei + E_EDGES;

    char* wsb = (char*)d_ws;
    size_t off = 0;
    auto alloc = [&](size_t bytes) -> char* {
        char* p = wsb + off;
        off += (bytes + 255) & ~(size_t)255;
        return p;
    };
    _Float16* h1f = (_Float16*)alloc((size_t)N_NODES * FDIM * 2); // fp16 gather rows (L1; L2 aliases)
    float* out1 = (float*)alloc((size_t)N_NODES * FDIM * 4);      // L1 GAT out; out2 aliases
    float* asrc = (float*)alloc((size_t)N_NODES * NHEAD * 4);     // L2: asrcH[K1][4][2]
    float* adst = (float*)alloc((size_t)N_NODES * NHEAD * 4);     // L2: adstH[K1][4][2]
    float* score= (float*)alloc((size_t)N_NODES * 4);
    float* invn = (float*)alloc(4);
    int* tmp  = (int*)alloc((size_t)N_NODES * 4);
    int* csr  = (int*)alloc((size_t)N_NODES * BSTRIDE * 4);
    int* remap= (int*)alloc((size_t)N_NODES * 4);
    int* oldi = (int*)alloc((size_t)K1_KEEP * 4);
    float* gsum = (float*)alloc(512 * 4);
    int* done = (int*)alloc(4);
    _Float16* a0p = (_Float16*)alloc((size_t)MPAD * FDIM * 2);  // fp16 hi plane
    _Float16* a1p = (_Float16*)alloc((size_t)MPAD * FDIM * 2);  // fp16 lo plane
    _Float16* w2t0 = (_Float16*)alloc((size_t)FDIM * FDIM * 2); // W2^T hi
    _Float16* w2t1 = (_Float16*)alloc((size_t)FDIM * FDIM * 2); // W2^T lo
    _Float16* h2f = h1f;   // L2 gather rows alias L1's (L1 reads done by then)
    float* out2 = out1;    // L2 GAT out aliases out1 (out1 reads done by then)

    // ---- layer 1 (GAT on N nodes, E edges + self loops) ----
    int gx1 = (N_NODES + 63) / 64;
    int ngemm1 = gx1 * 4;
    int nclr = (N_NODES + 255) / 256;
    gemm_tile<64, 128, 1, false, true><<<ngemm1 + nclr, 256, 0, stream>>>(x, W1, h1f,
            nullptr, nullptr, as1, ad1, asrc, adst, N_NODES,
            ngemm1, tmp, N_NODES, pw1, invn);
    prep_w2<<<256, 256, 0, stream>>>(W2, w2t0, w2t1);   // no deps; done early
    edge_fill<<<(E_EDGES + 255) / 256, 256, 0, stream>>>(src1, dst1, E_EDGES, tmp, csr);
    gat_fused<false><<<(N_NODES + 3) / 4, 256, 0, stream>>>(h1f, asrc, adst, tmp, csr,
            nullptr, nullptr, b1, pw1, invn, out1, score, N_NODES);

    // ---- pool 1; also preps pw2-norm + gsum/done for fused readout ----
    select_compact<<<1, 1024, 0, stream>>>(score, N_NODES, K1_KEEP, remap, oldi,
                                           gsum, done, pw2, invn);

    // ---- layer 2: gather+scale+split A, then fp16x2 MFMA GEMM ----
    prep_a<<<MPAD / 4, 256, 0, stream>>>(out1, oldi, score, a0p, a1p);
    gemm2_mfma<<<(MPAD / 128) * 4, 256, 0, stream>>>(a0p, a1p, w2t0, w2t1,
            as2, ad2, h2f, asrc, adst);
    gat_fused<true><<<(K1_KEEP + 3) / 4, 256, 0, stream>>>(h2f, asrc, adst, tmp, csr,
            oldi, remap, b2, pw2, invn, out2, score, K1_KEEP);

    // ---- pool 2 + fused readout ----
    select_compact<<<1, 1024, 0, stream>>>(score, K1_KEEP, K2_KEEP, remap, oldi,
                                           nullptr, nullptr, nullptr, nullptr);
    final_reduce<<<FR_GRID, 512, 0, stream>>>(out2, oldi, score, K2_KEEP, gsum, done,
                                              Wl, bl, (float*)d_out);
}

// Round 7
// 311.080 us; speedup vs baseline: 1.0619x; 1.0619x over previous
//
#include <hip/hip_runtime.h>
#include <math.h>

#define N_NODES 20000
#define E_EDGES 200000
#define K1_KEEP 10000
#define K2_KEEP 5000
#define HIDC 128
#define NHEAD 4
#define FDIM 512   // NHEAD*HIDC
#define NEG 0.2f
#define BSTRIDE 64 // bucket CSR stride; P(deg>64)~e^-64 for Binom(200k,1/20k)
#define SELCAP 20  // keys/thread in select (1024*20 >= 20000)
#define MPAD 10112 // 79*128: K1 rows padded to GEMM2 tile grid
#define FR_GRID 250 // final_reduce blocks: 250*40 == K1_KEEP
#define FR_RPB 40   // rows per block (contiguous stream)

typedef _Float16 half8 __attribute__((ext_vector_type(8)));
typedef _Float16 half4 __attribute__((ext_vector_type(4)));
typedef float f32x4 __attribute__((ext_vector_type(4)));

__device__ __forceinline__ float leaky(float x){ return x > 0.f ? x : NEG * x; }
__device__ __forceinline__ float elu(float x){ return x > 0.f ? x : expm1f(x); }
// monotone float->uint key (ascending)
__device__ __forceinline__ unsigned ordkey(float f){
    unsigned u = __float_as_uint(f);
    return (u & 0x80000000u) ? ~u : (u | 0x80000000u);
}

// ---------------- GEMM1 (fp32 vector path, layer 1 only) -------------------
// 64x128 tile / 256 threads / KC=32 LDS stage. Only instantiated for the
// K=64 layer-1 GEMM. AMODE 1: full attention dots in epilogue (fp32 acc).
// r4: h output stored as fp16 (gather consumer is service-rate-bound).
template<int K, int COLB, int AMODE, bool GATHER, bool CLEAR>
__global__ __launch_bounds__(256) void gemm_tile(const float* __restrict__ A,
        const float* __restrict__ W, _Float16* __restrict__ out,
        const int* __restrict__ gidx, const float* __restrict__ gsc,
        const float* __restrict__ avS, const float* __restrict__ avD,
        float* __restrict__ asrc, float* __restrict__ adst, int n,
        int ngemm, int* __restrict__ ctmp, int cn,
        const float* __restrict__ cw, float* __restrict__ cinvn)
{
    int t = threadIdx.x;
    int bid = blockIdx.x;
    if constexpr (CLEAR){
        if (bid >= ngemm){
            __shared__ float redc[4];
            int b2 = bid - ngemm;
            int i = b2 * 256 + t;
            if (i < cn) ctmp[i] = 0;
            if (b2 == 0){
                float s = cw[t] * cw[t] + cw[t + 256] * cw[t + 256];
#pragma unroll
                for (int off = 32; off > 0; off >>= 1) s += __shfl_xor(s, off);
                if ((t & 63) == 0) redc[t >> 6] = s;
                __syncthreads();
                if (t == 0) *cinvn = rsqrtf(redc[0] + redc[1] + redc[2] + redc[3]);
            }
            return;
        }
    }
    constexpr int NR = COLB / 16;
    constexpr int WPT = COLB / 32;
    constexpr int BPR = 512 / COLB;
    __shared__ float At[32][68];
    __shared__ float Wt[32][COLB];
    int row0 = (bid / BPR) * 64;
    int col0 = (bid % BPR) * COLB;
    int tr = t >> 4;
    int tc = t & 15;
    float acc[4][NR] = {};

    int arow[2]; float asc[2];
#pragma unroll
    for (int i = 0; i < 2; ++i){
        int r = (t + i * 256) >> 3;
        int gr = row0 + r;
        arow[i] = -1; asc[i] = 1.f;
        if (gr < n){
            if (GATHER){ arow[i] = gidx[gr]; asc[i] = gsc[arow[i]]; }
            else arow[i] = gr;
        }
    }

    float4 pa[2], pw[WPT];
#pragma unroll
    for (int i = 0; i < 2; ++i){
        int kq = (t + i * 256) & 7;
        pa[i] = make_float4(0.f, 0.f, 0.f, 0.f);
        if (arow[i] >= 0){
            pa[i] = *reinterpret_cast<const float4*>(&A[(size_t)arow[i] * K + kq * 4]);
            if (GATHER){ pa[i].x *= asc[i]; pa[i].y *= asc[i]; pa[i].z *= asc[i]; pa[i].w *= asc[i]; }
        }
    }
#pragma unroll
    for (int i = 0; i < WPT; ++i){
        int s = t + i * 256; int k = s / (COLB / 4), c4 = s % (COLB / 4);
        pw[i] = *reinterpret_cast<const float4*>(&W[(size_t)k * 512 + col0 + c4 * 4]);
    }

    for (int kc = 0; kc < K; kc += 32){
#pragma unroll
        for (int i = 0; i < 2; ++i){
            int s = t + i * 256; int r = s >> 3, kq = s & 7;
            At[kq * 4 + 0][r] = pa[i].x;
            At[kq * 4 + 1][r] = pa[i].y;
            At[kq * 4 + 2][r] = pa[i].z;
            At[kq * 4 + 3][r] = pa[i].w;
        }
#pragma unroll
        for (int i = 0; i < WPT; ++i){
            int s = t + i * 256; int k = s / (COLB / 4), c4 = s % (COLB / 4);
            *reinterpret_cast<float4*>(&Wt[k][c4 * 4]) = pw[i];
        }
        __syncthreads();
        if (kc + 32 < K){
            int kn = kc + 32;
#pragma unroll
            for (int i = 0; i < 2; ++i){
                int kq = (t + i * 256) & 7;
                pa[i] = make_float4(0.f, 0.f, 0.f, 0.f);
                if (arow[i] >= 0){
                    pa[i] = *reinterpret_cast<const float4*>(&A[(size_t)arow[i] * K + kn + kq * 4]);
                    if (GATHER){ pa[i].x *= asc[i]; pa[i].y *= asc[i]; pa[i].z *= asc[i]; pa[i].w *= asc[i]; }
                }
            }
#pragma unroll
            for (int i = 0; i < WPT; ++i){
                int s = t + i * 256; int k = s / (COLB / 4), c4 = s % (COLB / 4);
                pw[i] = *reinterpret_cast<const float4*>(&W[(size_t)(kn + k) * 512 + col0 + c4 * 4]);
            }
        }
#pragma unroll 8
        for (int kk = 0; kk < 32; ++kk){
            float4 a = *reinterpret_cast<const float4*>(&At[kk][tr * 4]);
            float af[4] = {a.x, a.y, a.z, a.w};
            float wf[NR];
            {
                float4 w0 = *reinterpret_cast<const float4*>(&Wt[kk][tc * 4]);
                wf[0] = w0.x; wf[1] = w0.y; wf[2] = w0.z; wf[3] = w0.w;
                if constexpr (NR == 8){
                    float4 w1 = *reinterpret_cast<const float4*>(&Wt[kk][tc * 4 + 64]);
                    wf[4] = w1.x; wf[5] = w1.y; wf[6] = w1.z; wf[7] = w1.w;
                }
            }
#pragma unroll
            for (int r = 0; r < 4; ++r)
#pragma unroll
                for (int c = 0; c < NR; ++c) acc[r][c] += af[r] * wf[c];
        }
        __syncthreads();
    }
#pragma unroll
    for (int r = 0; r < 4; ++r){
        int gr = row0 + 4 * tr + r;
        if (gr < n){
            half4 h0, h1q;
#pragma unroll
            for (int c = 0; c < 4; ++c) h0[c] = (_Float16)acc[r][c];
            *reinterpret_cast<half4*>(&out[(size_t)gr * 512 + col0 + tc * 4]) = h0;
            if constexpr (NR == 8){
#pragma unroll
                for (int c = 0; c < 4; ++c) h1q[c] = (_Float16)acc[r][4 + c];
                *reinterpret_cast<half4*>(&out[(size_t)gr * 512 + col0 + 64 + tc * 4]) = h1q;
            }
        }
    }
    if constexpr (AMODE == 1){
        int head = col0 >> 7;
        const float* as = avS + head * HIDC;
        const float* ad = avD + head * HIDC;
#pragma unroll
        for (int r = 0; r < 4; ++r){
            float s = 0.f, d = 0.f;
#pragma unroll
            for (int c = 0; c < 4; ++c){
                s += acc[r][c] * as[4 * tc + c];
                d += acc[r][c] * ad[4 * tc + c];
                s += acc[r][4 + c] * as[64 + 4 * tc + c];
                d += acc[r][4 + c] * ad[64 + 4 * tc + c];
            }
#pragma unroll
            for (int off = 1; off < 16; off <<= 1){ s += __shfl_xor(s, off); d += __shfl_xor(d, off); }
            int gr = row0 + 4 * tr + r;
            if (tc == 0 && gr < n){ asrc[gr * 4 + head] = s; adst[gr * 4 + head] = d; }
        }
    }
}

// --------- prep: transpose + fp16x2-split W2 -> W2T planes [n][k] ----------
__global__ __launch_bounds__(256) void prep_w2(const float* __restrict__ W2,
        _Float16* __restrict__ B0, _Float16* __restrict__ B1)
{
    __shared__ float tile[32][33];
    int bn = blockIdx.x & 15, bk = blockIdx.x >> 4;
    int n0 = bn * 32, k0 = bk * 32;
    int t = threadIdx.x;
    int j = t & 31, i0 = t >> 5;           // 8 row-groups of 32 cols
#pragma unroll
    for (int ii = 0; ii < 32; ii += 8)
        tile[i0 + ii][j] = W2[(size_t)(k0 + i0 + ii) * 512 + n0 + j];
    __syncthreads();
#pragma unroll
    for (int ii = 0; ii < 32; ii += 8){
        float v = tile[j][i0 + ii];        // = W2[k0+j][n0+i0+ii]
        _Float16 h0 = (_Float16)v;
        _Float16 h1 = (_Float16)(v - (float)h0);
        size_t o = (size_t)(n0 + i0 + ii) * 512 + k0 + j;
        B0[o] = h0; B1[o] = h1;
    }
}

// --------- prep: gather+scale+fp16x2-split A -> A planes [MPAD][512] -------
__global__ __launch_bounds__(256) void prep_a(const float* __restrict__ out1,
        const int* __restrict__ oldi, const float* __restrict__ score,
        _Float16* __restrict__ A0, _Float16* __restrict__ A1)
{
    int tid = blockIdx.x * 256 + threadIdx.x;   // MPAD*64 total
    int r = tid >> 6, kq = (tid & 63) << 3;
    half8 v0 = (half8)0, v1 = (half8)0;
    if (r < K1_KEEP){
        int o = oldi[r];
        float sc = score[o];
        const float4* p = reinterpret_cast<const float4*>(&out1[(size_t)o * 512 + kq]);
        float4 x0 = p[0], x1 = p[1];
        float vals[8] = {x0.x, x0.y, x0.z, x0.w, x1.x, x1.y, x1.z, x1.w};
#pragma unroll
        for (int j = 0; j < 8; ++j){
            float v = vals[j] * sc;
            _Float16 h = (_Float16)v;
            v0[j] = h;
            v1[j] = (_Float16)(v - (float)h);
        }
    }
    *reinterpret_cast<half8*>(&A0[(size_t)r * 512 + kq]) = v0;
    *reinterpret_cast<half8*>(&A1[(size_t)r * 512 + kq]) = v1;
}

// ---------------- GEMM2: fp16x2 split MFMA, 128x128 tile -------------------
// C[10000x512] = A@W2 via 3 products A0B0+A0B1+A1B0 in fp32 MFMA acc
// (~fp32 precision). Verified r2: GEMM2 fp32->MFMA cut total 467->406us.
// r4: C stored fp16 (consumed only by gat_fused's gather).
__global__ __launch_bounds__(256, 2) void gemm2_mfma(
        const _Float16* __restrict__ A0, const _Float16* __restrict__ A1,
        const _Float16* __restrict__ B0, const _Float16* __restrict__ B1,
        const float* __restrict__ avS, const float* __restrict__ avD,
        _Float16* __restrict__ C, float* __restrict__ asrc, float* __restrict__ adst)
{
    __shared__ _Float16 smem[2][4][128][32];   // 65536 B
    int t = threadIdx.x;
    int l = t & 63, w = t >> 6;
    int wr = w >> 1, wc = w & 1;
    int bidn = blockIdx.x & 3, bidm = blockIdx.x >> 2;
    int row0 = bidm * 128, col0 = bidn * 128;

    // wave w stages plane w: 0->A0 1->A1 2->B0 3->B1
    const _Float16* plane = (w == 0) ? A0 : (w == 1) ? A1 : (w == 2) ? B0 : B1;
    int prow0 = (w < 2) ? row0 : col0;
    int mloc = l >> 2;                        // row within 16-row stripe
    int gsw = (l & 3) ^ (mloc & 3);           // inverse-swizzled src granule
    const _Float16* gbase = plane + (size_t)(prow0 + mloc) * 512 + gsw * 8;

    f32x4 acc[4][4];
#pragma unroll
    for (int m = 0; m < 4; ++m)
#pragma unroll
        for (int n = 0; n < 4; ++n) acc[m][n] = (f32x4){0.f, 0.f, 0.f, 0.f};

    auto stage = [&](int buf, int chunk){
        const _Float16* src = gbase + chunk * 32;
        char* db = (char*)&smem[buf][w][0][0];
#pragma unroll
        for (int i = 0; i < 8; ++i)
            __builtin_amdgcn_global_load_lds(
                (const __attribute__((address_space(1))) void*)(src + (size_t)i * 8192),
                (__attribute__((address_space(3))) void*)(db + i * 1024), 16, 0, 0);
    };

    // frag read: row = l&15, k-granule = (l>>4) ^ swizzle(row&3) = (l>>4)^(l&3)
    int rb = (l & 15) * 64 + (((l >> 4) ^ (l & 3)) * 16);
    const char* sb = (const char*)smem;

    stage(0, 0);
    __syncthreads();
    for (int c = 0; c < 16; ++c){
        int buf = c & 1;
        if (c < 15) stage(buf ^ 1, c + 1);
        const char* base = sb + buf * 32768;
        half8 a0[4], a1[4], b0[4], b1[4];
#pragma unroll
        for (int m = 0; m < 4; ++m){
            a0[m] = *(const half8*)(base +         wr * 4096 + m * 1024 + rb);
            a1[m] = *(const half8*)(base +  8192 + wr * 4096 + m * 1024 + rb);
            b0[m] = *(const half8*)(base + 16384 + wc * 4096 + m * 1024 + rb);
            b1[m] = *(const half8*)(base + 24576 + wc * 4096 + m * 1024 + rb);
        }
        // product-major order: each acc reused every 16 MFMAs (no RAW stall)
#pragma unroll
        for (int m = 0; m < 4; ++m)
#pragma unroll
            for (int n = 0; n < 4; ++n)
                acc[m][n] = __builtin_amdgcn_mfma_f32_16x16x32_f16(a0[m], b0[n], acc[m][n], 0, 0, 0);
#pragma unroll
        for (int m = 0; m < 4; ++m)
#pragma unroll
            for (int n = 0; n < 4; ++n)
                acc[m][n] = __builtin_amdgcn_mfma_f32_16x16x32_f16(a0[m], b1[n], acc[m][n], 0, 0, 0);
#pragma unroll
        for (int m = 0; m < 4; ++m)
#pragma unroll
            for (int n = 0; n < 4; ++n)
                acc[m][n] = __builtin_amdgcn_mfma_f32_16x16x32_f16(a1[m], b0[n], acc[m][n], 0, 0, 0);
        __syncthreads();
    }

    // epilogue: C/D frag layout col=lane&15, row=(lane>>4)*4+reg (m89)
    int head = bidn;
    const float* asv = avS + head * HIDC + wc * 64;
    const float* adv = avD + head * HIDC + wc * 64;
    int lc = l & 15, lg = l >> 4;
    int rbase = row0 + wr * 64;
    int cbase = col0 + wc * 64;
#pragma unroll
    for (int m = 0; m < 4; ++m){
#pragma unroll
        for (int q = 0; q < 4; ++q){
            int row = rbase + m * 16 + lg * 4 + q;
            bool ok = row < K1_KEEP;
            float s = 0.f, d = 0.f;
#pragma unroll
            for (int n = 0; n < 4; ++n){
                float v = acc[m][n][q];
                int cc = n * 16 + lc;
                if (ok) C[(size_t)row * 512 + cbase + cc] = (_Float16)v;
                s += v * asv[cc];
                d += v * adv[cc];
            }
#pragma unroll
            for (int off = 1; off < 16; off <<= 1){
                s += __shfl_xor(s, off);
                d += __shfl_xor(d, off);
            }
            if (ok && lc == 0){
                asrc[row * 8 + head * 2 + wc] = s;   // half-pair layout [n][4][2]
                adst[row * 8 + head * 2 + wc] = d;
            }
        }
    }
}

// bucketed CSR fill: no count/scan passes needed; tmp returns degrees.
__global__ void edge_fill(const int* __restrict__ src, const int* __restrict__ dst, int e,
                          int* __restrict__ tmp, int* __restrict__ csr){
    int i = blockIdx.x * 256 + threadIdx.x;
    if (i >= e) return;
    int d = dst[i];
    int pos = atomicAdd(&tmp[d], 1);
    if (pos < BSTRIDE) csr[d * BSTRIDE + pos] = src[i];
}

// ---- fused softmax-stats + aggregation + pool score, one wave per node -----
// r4: h rows fp16 (16B/lane/edge) — gather service-rate-bound, bytes halved.
template<bool FILTER>
__global__ __launch_bounds__(256) void gat_fused(const _Float16* __restrict__ h,
        const float* __restrict__ asrc, const float* __restrict__ adst,
        const int* __restrict__ degs, const int* __restrict__ csr,
        const int* __restrict__ oldi, const int* __restrict__ remap,
        const float* __restrict__ bias, const float* __restrict__ pw,
        const float* __restrict__ invn, float* __restrict__ out,
        float* __restrict__ score, int n)
{
    int node = blockIdx.x * 4 + (threadIdx.x >> 6);
    int lane = threadIdx.x & 63;
    if (node >= n) return;
    int od = FILTER ? oldi[node] : node;
    int deg = degs[od]; if (deg > BSTRIDE) deg = BSTRIDE;
    int e0 = od * BSTRIDE;
    int ph = lane & 3;
    int pe = lane >> 2;
    float adn, sown;
    if (FILTER){
        float2 dv = *reinterpret_cast<const float2*>(&adst[(size_t)node * 8 + ph * 2]);
        float2 sv = *reinterpret_cast<const float2*>(&asrc[(size_t)node * 8 + ph * 2]);
        adn = dv.x + dv.y; sown = sv.x + sv.y;
    } else {
        adn = adst[node * 4 + ph]; sown = asrc[node * 4 + ph];
    }
    float slog = leaky(sown + adn);
    int sreg[4];
    float mx = slog;
#pragma unroll
    for (int blk = 0; blk < 4; ++blk){
        int j = blk * 16 + pe;
        int s = -1;
        if (j < deg){
            s = csr[e0 + j];
            if (FILTER) s = remap[s];
            if (s >= 0){
                float av;
                if (FILTER){
                    float2 v = *reinterpret_cast<const float2*>(&asrc[(size_t)s * 8 + ph * 2]);
                    av = v.x + v.y;
                } else av = asrc[s * 4 + ph];
                mx = fmaxf(mx, leaky(av + adn));
            }
        }
        sreg[blk] = s;
    }
#pragma unroll
    for (int off = 4; off < 64; off <<= 1) mx = fmaxf(mx, __shfl_xor(mx, off));
    float aexp[4];
    float lsum = 0.f;
#pragma unroll
    for (int blk = 0; blk < 4; ++blk){
        float ex = 0.f;
        int s = sreg[blk];
        if (s >= 0){
            float av;
            if (FILTER){
                float2 v = *reinterpret_cast<const float2*>(&asrc[(size_t)s * 8 + ph * 2]);
                av = v.x + v.y;
            } else av = asrc[s * 4 + ph];
            ex = expf(leaky(av + adn) - mx);
        }
        aexp[blk] = ex;
        lsum += ex;
    }
#pragma unroll
    for (int off = 4; off < 64; off <<= 1) lsum += __shfl_xor(lsum, off);
    float es  = expf(slog - mx);
    float inv = 1.f / (lsum + es);

    int f0 = lane * 8;
    int hf = lane >> 4;
    float invh  = __shfl(inv, hf);       // lane hf holds head hf's stats
    float aself = __shfl(es, hf) * invh;
    float4 acc0, acc1;
    {
        half8 v = *reinterpret_cast<const half8*>(&h[(size_t)node * FDIM + f0]);
        acc0 = make_float4(aself * (float)v[0], aself * (float)v[1],
                           aself * (float)v[2], aself * (float)v[3]);
        acc1 = make_float4(aself * (float)v[4], aself * (float)v[5],
                           aself * (float)v[6], aself * (float)v[7]);
    }
#pragma unroll
    for (int blk = 0; blk < 4; ++blk){
        int base = blk * 16;
        if (base >= deg) break;
        int cnt = deg - base; if (cnt > 16) cnt = 16;
        for (int e = 0; e < cnt; ++e){
            int s = __shfl(sreg[blk], e * 4);
            if (FILTER && s < 0) continue;
            float al = __shfl(aexp[blk], e * 4 + hf) * invh;
            half8 u = *reinterpret_cast<const half8*>(&h[(size_t)s * FDIM + f0]);
            acc0.x += al * (float)u[0]; acc0.y += al * (float)u[1];
            acc0.z += al * (float)u[2]; acc0.w += al * (float)u[3];
            acc1.x += al * (float)u[4]; acc1.y += al * (float)u[5];
            acc1.z += al * (float)u[6]; acc1.w += al * (float)u[7];
        }
    }
    const float4* bp = reinterpret_cast<const float4*>(&bias[f0]);
    float4 b0 = bp[0], b1 = bp[1];
    float4 o0 = make_float4(elu(acc0.x + b0.x), elu(acc0.y + b0.y),
                            elu(acc0.z + b0.z), elu(acc0.w + b0.w));
    float4 o1 = make_float4(elu(acc1.x + b1.x), elu(acc1.y + b1.y),
                            elu(acc1.z + b1.z), elu(acc1.w + b1.w));
    float4* op = reinterpret_cast<float4*>(&out[(size_t)node * FDIM + f0]);
    op[0] = o0; op[1] = o1;
    // fused TopK pool score
    const float4* wp = reinterpret_cast<const float4*>(&pw[f0]);
    float4 w0 = wp[0], w1 = wp[1];
    float s = o0.x * w0.x + o0.y * w0.y + o0.z * w0.z + o0.w * w0.w
            + o1.x * w1.x + o1.y * w1.y + o1.z * w1.z + o1.w * w1.w;
#pragma unroll
    for (int off = 32; off > 0; off >>= 1) s += __shfl_xor(s, off);
    if (lane == 0) score[node] = tanhf(s * (*invn));
}

// ---- exact top-k select (4x 8-bit radix) + compact, single block -----------
// r5: threshold scan parallelized (suffix-scan over 256 buckets); verified.
__global__ __launch_bounds__(1024) void select_compact(const float* __restrict__ score,
        int n, int k, int* __restrict__ remap, int* __restrict__ oldidx,
        float* __restrict__ gsum, int* __restrict__ done,
        const float* __restrict__ w, float* __restrict__ invn)
{
    __shared__ unsigned hist[16][256];
    __shared__ unsigned wtot[4];
    __shared__ unsigned s_prefix, s_rem, l_tie, l_keep;
    __shared__ float red2[16];
    int t = threadIdx.x;
    int wv = t >> 6;
    unsigned keys[SELCAP];
#pragma unroll
    for (int j = 0; j < SELCAP; ++j){
        int i = t + j * 1024;
        keys[j] = (i < n) ? ordkey(score[i]) : 0u;
    }
    if (t == 0){ s_prefix = 0u; s_rem = (unsigned)k; l_tie = 0u; l_keep = 0u; }
    for (int i = t; i < 16 * 256; i += 1024) ((unsigned*)hist)[i] = 0u;
    __syncthreads();
    for (int pass = 3; pass >= 0; --pass){
        unsigned shift = (unsigned)pass * 8u;
        unsigned pmask = (pass == 3) ? 0u : (0xFFFFFFFFu << (shift + 8u));
        unsigned pref = s_prefix;
        unsigned remv = s_rem;           // all threads read before any write
#pragma unroll
        for (int j = 0; j < SELCAP; ++j){
            int i = t + j * 1024;
            if (i < n && (keys[j] & pmask) == pref)
                atomicAdd(&hist[wv][(keys[j] >> shift) & 255u], 1u);
        }
        __syncthreads();
        unsigned c = 0, v = 0;
        if (t < 256){
            unsigned a = 0;
#pragma unroll
            for (int wq = 0; wq < 16; ++wq) a += hist[wq][t];
            c = a; v = a;
            // inclusive suffix scan within this wave's 64-bucket chunk
#pragma unroll
            for (int off = 1; off < 64; off <<= 1){
                unsigned o = __shfl_down(v, off);
                if ((t & 63) + off < 64) v += o;
            }
            if ((t & 63) == 0) wtot[t >> 6] = v;   // chunk total (lane 0 = full suffix of chunk)
        }
        __syncthreads();
        if (t < 256){
#pragma unroll
            for (int q = 0; q < 4; ++q)
                if (q > (t >> 6)) v += wtot[q];    // add totals of higher chunks
            unsigned nxt = v - c;                   // suffix(t+1)
            if (v >= remv && nxt < remv){           // unique: suffix monotone
                s_prefix = pref | ((unsigned)t << shift);
                s_rem = remv - nxt;
            }
        }
        __syncthreads();
        if (pass > 0){
            for (int i = t; i < 16 * 256; i += 1024) ((unsigned*)hist)[i] = 0u;
            __syncthreads();
        }
    }
    unsigned T = s_prefix, ties = s_rem;
#pragma unroll
    for (int j = 0; j < SELCAP; ++j){
        int i = t + j * 1024;
        if (i >= n) continue;
        unsigned key = keys[j];
        int keep = 0;
        if (key > T) keep = 1;
        else if (key == T){
            unsigned tk = atomicAdd(&l_tie, 1u);
            if (tk < ties) keep = 1;
        }
        if (keep){
            int pos = (int)atomicAdd(&l_keep, 1u);
            remap[i] = pos;
            oldidx[pos] = i;
        } else remap[i] = -1;
    }
    if (gsum){
        if (t < 512) gsum[t] = 0.f;
        if (t == 0) *done = 0;
        float s = (t < 512) ? w[t] * w[t] : 0.f;
#pragma unroll
        for (int off = 32; off > 0; off >>= 1) s += __shfl_xor(s, off);
        if ((t & 63) == 0) red2[wv] = s;
        __syncthreads();
        if (t == 0){
            float a = 0.f;
            for (int i = 0; i < 16; ++i) a += red2[i];
            *invn = rsqrtf(a);
        }
    }
}

// --------- readout: mean-pool reduce + final 512x10 GEMM (last block) -------
// r7: REWRITE after two failed shapes. r5 (64 blk, oldidx gather): 48us
// dependent-chain bound. r6 (512 blk, atomics into one gsum[512]): 70us —
// same-LINE atomic serialization (~20cy/op/line x 8192 ops/line = 68us).
// Now: stream ALL K1 rows sequentially (coalesced, no index->row chain)
// masked by remap>=0; per-block partials into PRIVATE pg[bid][512] slots
// (distinct lines, zero contention) with device-scope atomic store/load
// (per-XCD L2s non-coherent — plain stores from other XCDs invisible).
__global__ __launch_bounds__(512) void final_reduce(const float* __restrict__ x,
        const int* __restrict__ remap, const float* __restrict__ score,
        float* __restrict__ pg, int* __restrict__ done,
        const float* __restrict__ Wl, const float* __restrict__ bl,
        float* __restrict__ out)
{
    __shared__ float gsh[512];
    __shared__ int last;
    int t = threadIdx.x; // 512
    int r0 = blockIdx.x * FR_RPB;
    float a = 0.f;
#pragma unroll
    for (int i = 0; i < FR_RPB; i += 4){
        int rr = r0 + i;
        float s0 = (remap[rr + 0] >= 0) ? score[rr + 0] : 0.f;
        float s1 = (remap[rr + 1] >= 0) ? score[rr + 1] : 0.f;
        float s2 = (remap[rr + 2] >= 0) ? score[rr + 2] : 0.f;
        float s3 = (remap[rr + 3] >= 0) ? score[rr + 3] : 0.f;
        float v0 = x[(size_t)(rr + 0) * FDIM + t];
        float v1 = x[(size_t)(rr + 1) * FDIM + t];
        float v2 = x[(size_t)(rr + 2) * FDIM + t];
        float v3 = x[(size_t)(rr + 3) * FDIM + t];
        a += v0 * s0 + v1 * s1 + v2 * s2 + v3 * s3;
    }
    __hip_atomic_store(&pg[(size_t)blockIdx.x * 512 + t], a,
                       __ATOMIC_RELAXED, __HIP_MEMORY_SCOPE_AGENT);
    __threadfence();
    if (t == 0) last = (atomicAdd(done, 1) == (int)gridDim.x - 1);
    __syncthreads();
    if (!last) return;
    // last block: device-scope loads give coherent view of all partials
    float a2 = 0.f;
#pragma unroll 10
    for (int b = 0; b < FR_GRID; ++b)
        a2 += __hip_atomic_load(&pg[(size_t)b * 512 + t],
                                __ATOMIC_RELAXED, __HIP_MEMORY_SCOPE_AGENT);
    gsh[t] = a2;
    __syncthreads();
    int wv = t >> 6, lane = t & 63;
    for (int w = wv; w < 10; w += 8){
        float s = 0.f;
        for (int f = lane; f < FDIM; f += 64) s += gsh[f] * Wl[f * 10 + w];
#pragma unroll
        for (int off = 32; off > 0; off >>= 1) s += __shfl_xor(s, off);
        if (lane == 0) out[w] = s * (1.0f / K2_KEEP) + bl[w];
    }
}

extern "C" void kernel_launch(void* const* d_in, const int* in_sizes, int n_in,
                              void* d_out, int out_size, void* d_ws, size_t ws_size,
                              hipStream_t stream)
{
    (void)in_sizes; (void)n_in; (void)out_size; (void)ws_size;
    const float* x   = (const float*)d_in[0];
    const int*   ei  = (const int*)  d_in[1];
    const float* W1  = (const float*)d_in[3];
    const float* as1 = (const float*)d_in[4];
    const float* ad1 = (const float*)d_in[5];
    const float* b1  = (const float*)d_in[6];
    const float* pw1 = (const float*)d_in[7];
    const float* W2  = (const float*)d_in[8];
    const float* as2 = (const float*)d_in[9];
    const float* ad2 = (const float*)d_in[10];
    const float* b2  = (const float*)d_in[11];
    const float* pw2 = (const float*)d_in[12];
    const float* Wl  = (const float*)d_in[13];
    const float* bl  = (const float*)d_in[14];
    const int* src1 = ei;
    const int* dst1 = ei + E_EDGES;

    char* wsb = (char*)d_ws;
    size_t off = 0;
    auto alloc = [&](size_t bytes) -> char* {
        char* p = wsb + off;
        off += (bytes + 255) & ~(size_t)255;
        return p;
    };
    _Float16* h1f = (_Float16*)alloc((size_t)N_NODES * FDIM * 2); // fp16 gather rows (L1; L2 aliases)
    float* out1 = (float*)alloc((size_t)N_NODES * FDIM * 4);      // L1 GAT out; out2 aliases
    float* asrc = (float*)alloc((size_t)N_NODES * NHEAD * 4);     // L2: asrcH[K1][4][2]
    float* adst = (float*)alloc((size_t)N_NODES * NHEAD * 4);     // L2: adstH[K1][4][2]
    float* score= (float*)alloc((size_t)N_NODES * 4);
    float* invn = (float*)alloc(4);
    int* tmp  = (int*)alloc((size_t)N_NODES * 4);
    int* csr  = (int*)alloc((size_t)N_NODES * BSTRIDE * 4);
    int* remap= (int*)alloc((size_t)N_NODES * 4);
    int* oldi = (int*)alloc((size_t)K1_KEEP * 4);
    float* gsum = (float*)alloc(512 * 4);
    int* done = (int*)alloc(4);
    float* pg = (float*)alloc((size_t)FR_GRID * 512 * 4);       // per-block partials
    _Float16* a0p = (_Float16*)alloc((size_t)MPAD * FDIM * 2);  // fp16 hi plane
    _Float16* a1p = (_Float16*)alloc((size_t)MPAD * FDIM * 2);  // fp16 lo plane
    _Float16* w2t0 = (_Float16*)alloc((size_t)FDIM * FDIM * 2); // W2^T hi
    _Float16* w2t1 = (_Float16*)alloc((size_t)FDIM * FDIM * 2); // W2^T lo
    _Float16* h2f = h1f;   // L2 gather rows alias L1's (L1 reads done by then)
    float* out2 = out1;    // L2 GAT out aliases out1 (out1 reads done by then)

    // ---- layer 1 (GAT on N nodes, E edges + self loops) ----
    int gx1 = (N_NODES + 63) / 64;
    int ngemm1 = gx1 * 4;
    int nclr = (N_NODES + 255) / 256;
    gemm_tile<64, 128, 1, false, true><<<ngemm1 + nclr, 256, 0, stream>>>(x, W1, h1f,
            nullptr, nullptr, as1, ad1, asrc, adst, N_NODES,
            ngemm1, tmp, N_NODES, pw1, invn);
    prep_w2<<<256, 256, 0, stream>>>(W2, w2t0, w2t1);   // no deps; done early
    edge_fill<<<(E_EDGES + 255) / 256, 256, 0, stream>>>(src1, dst1, E_EDGES, tmp, csr);
    gat_fused<false><<<(N_NODES + 3) / 4, 256, 0, stream>>>(h1f, asrc, adst, tmp, csr,
            nullptr, nullptr, b1, pw1, invn, out1, score, N_NODES);

    // ---- pool 1; also preps pw2-norm + gsum/done for fused readout ----
    select_compact<<<1, 1024, 0, stream>>>(score, N_NODES, K1_KEEP, remap, oldi,
                                           gsum, done, pw2, invn);

    // ---- layer 2: gather+scale+split A, then fp16x2 MFMA GEMM ----
    prep_a<<<MPAD / 4, 256, 0, stream>>>(out1, oldi, score, a0p, a1p);
    gemm2_mfma<<<(MPAD / 128) * 4, 256, 0, stream>>>(a0p, a1p, w2t0, w2t1,
            as2, ad2, h2f, asrc, adst);
    gat_fused<true><<<(K1_KEEP + 3) / 4, 256, 0, stream>>>(h2f, asrc, adst, tmp, csr,
            oldi, remap, b2, pw2, invn, out2, score, K1_KEEP);

    // ---- pool 2 + fused readout (masked stream over all K1 rows) ----
    select_compact<<<1, 1024, 0, stream>>>(score, K1_KEEP, K2_KEEP, remap, oldi,
                                           nullptr, nullptr, nullptr, nullptr);
    final_reduce<<<FR_GRID, 512, 0, stream>>>(out2, remap, score, pg, done,
                                              Wl, bl, (float*)d_out);
}

// Round 8
// 274.228 us; speedup vs baseline: 1.2046x; 1.1344x over previous
//
#include <hip/hip_runtime.h>
#include <math.h>

#define N_NODES 20000
#define E_EDGES 200000
#define K1_KEEP 10000
#define K2_KEEP 5000
#define HIDC 128
#define NHEAD 4
#define FDIM 512   // NHEAD*HIDC
#define NEG 0.2f
#define BSTRIDE 64 // bucket CSR stride; P(deg>64)~e^-64 for Binom(200k,1/20k)
#define SELCAP 20  // keys/thread in select (1024*20 >= 20000)
#define MPAD 10112 // 79*128: K1 rows padded to GEMM2 tile grid
#define FR_GRID 250 // final_reduce blocks: 250*40 == K1_KEEP
#define FR_RPB 40   // rows per block (contiguous stream)

typedef _Float16 half8 __attribute__((ext_vector_type(8)));
typedef _Float16 half4 __attribute__((ext_vector_type(4)));
typedef float f32x4 __attribute__((ext_vector_type(4)));

__device__ __forceinline__ float leaky(float x){ return x > 0.f ? x : NEG * x; }
__device__ __forceinline__ float elu(float x){ return x > 0.f ? x : expm1f(x); }
// monotone float->uint key (ascending)
__device__ __forceinline__ unsigned ordkey(float f){
    unsigned u = __float_as_uint(f);
    return (u & 0x80000000u) ? ~u : (u | 0x80000000u);
}

// ---------------- GEMM1 (fp32 vector path, layer 1 only) -------------------
// 64x128 tile / 256 threads / KC=32 LDS stage. Only instantiated for the
// K=64 layer-1 GEMM. AMODE 1: full attention dots in epilogue (fp32 acc).
// r4: h output stored as fp16 (gather consumer is service-rate-bound).
template<int K, int COLB, int AMODE, bool GATHER, bool CLEAR>
__global__ __launch_bounds__(256) void gemm_tile(const float* __restrict__ A,
        const float* __restrict__ W, _Float16* __restrict__ out,
        const int* __restrict__ gidx, const float* __restrict__ gsc,
        const float* __restrict__ avS, const float* __restrict__ avD,
        float* __restrict__ asrc, float* __restrict__ adst, int n,
        int ngemm, int* __restrict__ ctmp, int cn,
        const float* __restrict__ cw, float* __restrict__ cinvn)
{
    int t = threadIdx.x;
    int bid = blockIdx.x;
    if constexpr (CLEAR){
        if (bid >= ngemm){
            __shared__ float redc[4];
            int b2 = bid - ngemm;
            int i = b2 * 256 + t;
            if (i < cn) ctmp[i] = 0;
            if (b2 == 0){
                float s = cw[t] * cw[t] + cw[t + 256] * cw[t + 256];
#pragma unroll
                for (int off = 32; off > 0; off >>= 1) s += __shfl_xor(s, off);
                if ((t & 63) == 0) redc[t >> 6] = s;
                __syncthreads();
                if (t == 0) *cinvn = rsqrtf(redc[0] + redc[1] + redc[2] + redc[3]);
            }
            return;
        }
    }
    constexpr int NR = COLB / 16;
    constexpr int WPT = COLB / 32;
    constexpr int BPR = 512 / COLB;
    __shared__ float At[32][68];
    __shared__ float Wt[32][COLB];
    int row0 = (bid / BPR) * 64;
    int col0 = (bid % BPR) * COLB;
    int tr = t >> 4;
    int tc = t & 15;
    float acc[4][NR] = {};

    int arow[2]; float asc[2];
#pragma unroll
    for (int i = 0; i < 2; ++i){
        int r = (t + i * 256) >> 3;
        int gr = row0 + r;
        arow[i] = -1; asc[i] = 1.f;
        if (gr < n){
            if (GATHER){ arow[i] = gidx[gr]; asc[i] = gsc[arow[i]]; }
            else arow[i] = gr;
        }
    }

    float4 pa[2], pw[WPT];
#pragma unroll
    for (int i = 0; i < 2; ++i){
        int kq = (t + i * 256) & 7;
        pa[i] = make_float4(0.f, 0.f, 0.f, 0.f);
        if (arow[i] >= 0){
            pa[i] = *reinterpret_cast<const float4*>(&A[(size_t)arow[i] * K + kq * 4]);
            if (GATHER){ pa[i].x *= asc[i]; pa[i].y *= asc[i]; pa[i].z *= asc[i]; pa[i].w *= asc[i]; }
        }
    }
#pragma unroll
    for (int i = 0; i < WPT; ++i){
        int s = t + i * 256; int k = s / (COLB / 4), c4 = s % (COLB / 4);
        pw[i] = *reinterpret_cast<const float4*>(&W[(size_t)k * 512 + col0 + c4 * 4]);
    }

    for (int kc = 0; kc < K; kc += 32){
#pragma unroll
        for (int i = 0; i < 2; ++i){
            int s = t + i * 256; int r = s >> 3, kq = s & 7;
            At[kq * 4 + 0][r] = pa[i].x;
            At[kq * 4 + 1][r] = pa[i].y;
            At[kq * 4 + 2][r] = pa[i].z;
            At[kq * 4 + 3][r] = pa[i].w;
        }
#pragma unroll
        for (int i = 0; i < WPT; ++i){
            int s = t + i * 256; int k = s / (COLB / 4), c4 = s % (COLB / 4);
            *reinterpret_cast<float4*>(&Wt[k][c4 * 4]) = pw[i];
        }
        __syncthreads();
        if (kc + 32 < K){
            int kn = kc + 32;
#pragma unroll
            for (int i = 0; i < 2; ++i){
                int kq = (t + i * 256) & 7;
                pa[i] = make_float4(0.f, 0.f, 0.f, 0.f);
                if (arow[i] >= 0){
                    pa[i] = *reinterpret_cast<const float4*>(&A[(size_t)arow[i] * K + kn + kq * 4]);
                    if (GATHER){ pa[i].x *= asc[i]; pa[i].y *= asc[i]; pa[i].z *= asc[i]; pa[i].w *= asc[i]; }
                }
            }
#pragma unroll
            for (int i = 0; i < WPT; ++i){
                int s = t + i * 256; int k = s / (COLB / 4), c4 = s % (COLB / 4);
                pw[i] = *reinterpret_cast<const float4*>(&W[(size_t)(kn + k) * 512 + col0 + c4 * 4]);
            }
        }
#pragma unroll 8
        for (int kk = 0; kk < 32; ++kk){
            float4 a = *reinterpret_cast<const float4*>(&At[kk][tr * 4]);
            float af[4] = {a.x, a.y, a.z, a.w};
            float wf[NR];
            {
                float4 w0 = *reinterpret_cast<const float4*>(&Wt[kk][tc * 4]);
                wf[0] = w0.x; wf[1] = w0.y; wf[2] = w0.z; wf[3] = w0.w;
                if constexpr (NR == 8){
                    float4 w1 = *reinterpret_cast<const float4*>(&Wt[kk][tc * 4 + 64]);
                    wf[4] = w1.x; wf[5] = w1.y; wf[6] = w1.z; wf[7] = w1.w;
                }
            }
#pragma unroll
            for (int r = 0; r < 4; ++r)
#pragma unroll
                for (int c = 0; c < NR; ++c) acc[r][c] += af[r] * wf[c];
        }
        __syncthreads();
    }
#pragma unroll
    for (int r = 0; r < 4; ++r){
        int gr = row0 + 4 * tr + r;
        if (gr < n){
            half4 h0, h1q;
#pragma unroll
            for (int c = 0; c < 4; ++c) h0[c] = (_Float16)acc[r][c];
            *reinterpret_cast<half4*>(&out[(size_t)gr * 512 + col0 + tc * 4]) = h0;
            if constexpr (NR == 8){
#pragma unroll
                for (int c = 0; c < 4; ++c) h1q[c] = (_Float16)acc[r][4 + c];
                *reinterpret_cast<half4*>(&out[(size_t)gr * 512 + col0 + 64 + tc * 4]) = h1q;
            }
        }
    }
    if constexpr (AMODE == 1){
        int head = col0 >> 7;
        const float* as = avS + head * HIDC;
        const float* ad = avD + head * HIDC;
#pragma unroll
        for (int r = 0; r < 4; ++r){
            float s = 0.f, d = 0.f;
#pragma unroll
            for (int c = 0; c < 4; ++c){
                s += acc[r][c] * as[4 * tc + c];
                d += acc[r][c] * ad[4 * tc + c];
                s += acc[r][4 + c] * as[64 + 4 * tc + c];
                d += acc[r][4 + c] * ad[64 + 4 * tc + c];
            }
#pragma unroll
            for (int off = 1; off < 16; off <<= 1){ s += __shfl_xor(s, off); d += __shfl_xor(d, off); }
            int gr = row0 + 4 * tr + r;
            if (tc == 0 && gr < n){ asrc[gr * 4 + head] = s; adst[gr * 4 + head] = d; }
        }
    }
}

// --------- prep: transpose + fp16x2-split W2 -> W2T planes [n][k] ----------
__global__ __launch_bounds__(256) void prep_w2(const float* __restrict__ W2,
        _Float16* __restrict__ B0, _Float16* __restrict__ B1)
{
    __shared__ float tile[32][33];
    int bn = blockIdx.x & 15, bk = blockIdx.x >> 4;
    int n0 = bn * 32, k0 = bk * 32;
    int t = threadIdx.x;
    int j = t & 31, i0 = t >> 5;           // 8 row-groups of 32 cols
#pragma unroll
    for (int ii = 0; ii < 32; ii += 8)
        tile[i0 + ii][j] = W2[(size_t)(k0 + i0 + ii) * 512 + n0 + j];
    __syncthreads();
#pragma unroll
    for (int ii = 0; ii < 32; ii += 8){
        float v = tile[j][i0 + ii];        // = W2[k0+j][n0+i0+ii]
        _Float16 h0 = (_Float16)v;
        _Float16 h1 = (_Float16)(v - (float)h0);
        size_t o = (size_t)(n0 + i0 + ii) * 512 + k0 + j;
        B0[o] = h0; B1[o] = h1;
    }
}

// --------- prep: gather+scale+fp16x2-split A -> A planes [MPAD][512] -------
__global__ __launch_bounds__(256) void prep_a(const float* __restrict__ out1,
        const int* __restrict__ oldi, const float* __restrict__ score,
        _Float16* __restrict__ A0, _Float16* __restrict__ A1)
{
    int tid = blockIdx.x * 256 + threadIdx.x;   // MPAD*64 total
    int r = tid >> 6, kq = (tid & 63) << 3;
    half8 v0 = (half8)0, v1 = (half8)0;
    if (r < K1_KEEP){
        int o = oldi[r];
        float sc = score[o];
        const float4* p = reinterpret_cast<const float4*>(&out1[(size_t)o * 512 + kq]);
        float4 x0 = p[0], x1 = p[1];
        float vals[8] = {x0.x, x0.y, x0.z, x0.w, x1.x, x1.y, x1.z, x1.w};
#pragma unroll
        for (int j = 0; j < 8; ++j){
            float v = vals[j] * sc;
            _Float16 h = (_Float16)v;
            v0[j] = h;
            v1[j] = (_Float16)(v - (float)h);
        }
    }
    *reinterpret_cast<half8*>(&A0[(size_t)r * 512 + kq]) = v0;
    *reinterpret_cast<half8*>(&A1[(size_t)r * 512 + kq]) = v1;
}

// ---------------- GEMM2: fp16x2 split MFMA, 128x128 tile -------------------
// C[10000x512] = A@W2 via 3 products A0B0+A0B1+A1B0 in fp32 MFMA acc
// (~fp32 precision). Verified r2: GEMM2 fp32->MFMA cut total 467->406us.
// r4: C stored fp16 (consumed only by gat_fused's gather).
__global__ __launch_bounds__(256, 2) void gemm2_mfma(
        const _Float16* __restrict__ A0, const _Float16* __restrict__ A1,
        const _Float16* __restrict__ B0, const _Float16* __restrict__ B1,
        const float* __restrict__ avS, const float* __restrict__ avD,
        _Float16* __restrict__ C, float* __restrict__ asrc, float* __restrict__ adst)
{
    __shared__ _Float16 smem[2][4][128][32];   // 65536 B
    int t = threadIdx.x;
    int l = t & 63, w = t >> 6;
    int wr = w >> 1, wc = w & 1;
    int bidn = blockIdx.x & 3, bidm = blockIdx.x >> 2;
    int row0 = bidm * 128, col0 = bidn * 128;

    // wave w stages plane w: 0->A0 1->A1 2->B0 3->B1
    const _Float16* plane = (w == 0) ? A0 : (w == 1) ? A1 : (w == 2) ? B0 : B1;
    int prow0 = (w < 2) ? row0 : col0;
    int mloc = l >> 2;                        // row within 16-row stripe
    int gsw = (l & 3) ^ (mloc & 3);           // inverse-swizzled src granule
    const _Float16* gbase = plane + (size_t)(prow0 + mloc) * 512 + gsw * 8;

    f32x4 acc[4][4];
#pragma unroll
    for (int m = 0; m < 4; ++m)
#pragma unroll
        for (int n = 0; n < 4; ++n) acc[m][n] = (f32x4){0.f, 0.f, 0.f, 0.f};

    auto stage = [&](int buf, int chunk){
        const _Float16* src = gbase + chunk * 32;
        char* db = (char*)&smem[buf][w][0][0];
#pragma unroll
        for (int i = 0; i < 8; ++i)
            __builtin_amdgcn_global_load_lds(
                (const __attribute__((address_space(1))) void*)(src + (size_t)i * 8192),
                (__attribute__((address_space(3))) void*)(db + i * 1024), 16, 0, 0);
    };

    // frag read: row = l&15, k-granule = (l>>4) ^ swizzle(row&3) = (l>>4)^(l&3)
    int rb = (l & 15) * 64 + (((l >> 4) ^ (l & 3)) * 16);
    const char* sb = (const char*)smem;

    stage(0, 0);
    __syncthreads();
    for (int c = 0; c < 16; ++c){
        int buf = c & 1;
        if (c < 15) stage(buf ^ 1, c + 1);
        const char* base = sb + buf * 32768;
        half8 a0[4], a1[4], b0[4], b1[4];
#pragma unroll
        for (int m = 0; m < 4; ++m){
            a0[m] = *(const half8*)(base +         wr * 4096 + m * 1024 + rb);
            a1[m] = *(const half8*)(base +  8192 + wr * 4096 + m * 1024 + rb);
            b0[m] = *(const half8*)(base + 16384 + wc * 4096 + m * 1024 + rb);
            b1[m] = *(const half8*)(base + 24576 + wc * 4096 + m * 1024 + rb);
        }
        // product-major order: each acc reused every 16 MFMAs (no RAW stall)
#pragma unroll
        for (int m = 0; m < 4; ++m)
#pragma unroll
            for (int n = 0; n < 4; ++n)
                acc[m][n] = __builtin_amdgcn_mfma_f32_16x16x32_f16(a0[m], b0[n], acc[m][n], 0, 0, 0);
#pragma unroll
        for (int m = 0; m < 4; ++m)
#pragma unroll
            for (int n = 0; n < 4; ++n)
                acc[m][n] = __builtin_amdgcn_mfma_f32_16x16x32_f16(a0[m], b1[n], acc[m][n], 0, 0, 0);
#pragma unroll
        for (int m = 0; m < 4; ++m)
#pragma unroll
            for (int n = 0; n < 4; ++n)
                acc[m][n] = __builtin_amdgcn_mfma_f32_16x16x32_f16(a1[m], b0[n], acc[m][n], 0, 0, 0);
        __syncthreads();
    }

    // epilogue: C/D frag layout col=lane&15, row=(lane>>4)*4+reg (m89)
    int head = bidn;
    const float* asv = avS + head * HIDC + wc * 64;
    const float* adv = avD + head * HIDC + wc * 64;
    int lc = l & 15, lg = l >> 4;
    int rbase = row0 + wr * 64;
    int cbase = col0 + wc * 64;
#pragma unroll
    for (int m = 0; m < 4; ++m){
#pragma unroll
        for (int q = 0; q < 4; ++q){
            int row = rbase + m * 16 + lg * 4 + q;
            bool ok = row < K1_KEEP;
            float s = 0.f, d = 0.f;
#pragma unroll
            for (int n = 0; n < 4; ++n){
                float v = acc[m][n][q];
                int cc = n * 16 + lc;
                if (ok) C[(size_t)row * 512 + cbase + cc] = (_Float16)v;
                s += v * asv[cc];
                d += v * adv[cc];
            }
#pragma unroll
            for (int off = 1; off < 16; off <<= 1){
                s += __shfl_xor(s, off);
                d += __shfl_xor(d, off);
            }
            if (ok && lc == 0){
                asrc[row * 8 + head * 2 + wc] = s;   // half-pair layout [n][4][2]
                adst[row * 8 + head * 2 + wc] = d;
            }
        }
    }
}

// bucketed CSR fill: no count/scan passes needed; tmp returns degrees.
__global__ void edge_fill(const int* __restrict__ src, const int* __restrict__ dst, int e,
                          int* __restrict__ tmp, int* __restrict__ csr){
    int i = blockIdx.x * 256 + threadIdx.x;
    if (i >= e) return;
    int d = dst[i];
    int pos = atomicAdd(&tmp[d], 1);
    if (pos < BSTRIDE) csr[d * BSTRIDE + pos] = src[i];
}

// ---- fused softmax-stats + aggregation + pool score, one wave per node -----
// r4: h rows fp16 (16B/lane/edge) — gather service-rate-bound, bytes halved.
template<bool FILTER>
__global__ __launch_bounds__(256) void gat_fused(const _Float16* __restrict__ h,
        const float* __restrict__ asrc, const float* __restrict__ adst,
        const int* __restrict__ degs, const int* __restrict__ csr,
        const int* __restrict__ oldi, const int* __restrict__ remap,
        const float* __restrict__ bias, const float* __restrict__ pw,
        const float* __restrict__ invn, float* __restrict__ out,
        float* __restrict__ score, int n)
{
    int node = blockIdx.x * 4 + (threadIdx.x >> 6);
    int lane = threadIdx.x & 63;
    if (node >= n) return;
    int od = FILTER ? oldi[node] : node;
    int deg = degs[od]; if (deg > BSTRIDE) deg = BSTRIDE;
    int e0 = od * BSTRIDE;
    int ph = lane & 3;
    int pe = lane >> 2;
    float adn, sown;
    if (FILTER){
        float2 dv = *reinterpret_cast<const float2*>(&adst[(size_t)node * 8 + ph * 2]);
        float2 sv = *reinterpret_cast<const float2*>(&asrc[(size_t)node * 8 + ph * 2]);
        adn = dv.x + dv.y; sown = sv.x + sv.y;
    } else {
        adn = adst[node * 4 + ph]; sown = asrc[node * 4 + ph];
    }
    float slog = leaky(sown + adn);
    int sreg[4];
    float mx = slog;
#pragma unroll
    for (int blk = 0; blk < 4; ++blk){
        int j = blk * 16 + pe;
        int s = -1;
        if (j < deg){
            s = csr[e0 + j];
            if (FILTER) s = remap[s];
            if (s >= 0){
                float av;
                if (FILTER){
                    float2 v = *reinterpret_cast<const float2*>(&asrc[(size_t)s * 8 + ph * 2]);
                    av = v.x + v.y;
                } else av = asrc[s * 4 + ph];
                mx = fmaxf(mx, leaky(av + adn));
            }
        }
        sreg[blk] = s;
    }
#pragma unroll
    for (int off = 4; off < 64; off <<= 1) mx = fmaxf(mx, __shfl_xor(mx, off));
    float aexp[4];
    float lsum = 0.f;
#pragma unroll
    for (int blk = 0; blk < 4; ++blk){
        float ex = 0.f;
        int s = sreg[blk];
        if (s >= 0){
            float av;
            if (FILTER){
                float2 v = *reinterpret_cast<const float2*>(&asrc[(size_t)s * 8 + ph * 2]);
                av = v.x + v.y;
            } else av = asrc[s * 4 + ph];
            ex = expf(leaky(av + adn) - mx);
        }
        aexp[blk] = ex;
        lsum += ex;
    }
#pragma unroll
    for (int off = 4; off < 64; off <<= 1) lsum += __shfl_xor(lsum, off);
    float es  = expf(slog - mx);
    float inv = 1.f / (lsum + es);

    int f0 = lane * 8;
    int hf = lane >> 4;
    float invh  = __shfl(inv, hf);       // lane hf holds head hf's stats
    float aself = __shfl(es, hf) * invh;
    float4 acc0, acc1;
    {
        half8 v = *reinterpret_cast<const half8*>(&h[(size_t)node * FDIM + f0]);
        acc0 = make_float4(aself * (float)v[0], aself * (float)v[1],
                           aself * (float)v[2], aself * (float)v[3]);
        acc1 = make_float4(aself * (float)v[4], aself * (float)v[5],
                           aself * (float)v[6], aself * (float)v[7]);
    }
#pragma unroll
    for (int blk = 0; blk < 4; ++blk){
        int base = blk * 16;
        if (base >= deg) break;
        int cnt = deg - base; if (cnt > 16) cnt = 16;
        for (int e = 0; e < cnt; ++e){
            int s = __shfl(sreg[blk], e * 4);
            if (FILTER && s < 0) continue;
            float al = __shfl(aexp[blk], e * 4 + hf) * invh;
            half8 u = *reinterpret_cast<const half8*>(&h[(size_t)s * FDIM + f0]);
            acc0.x += al * (float)u[0]; acc0.y += al * (float)u[1];
            acc0.z += al * (float)u[2]; acc0.w += al * (float)u[3];
            acc1.x += al * (float)u[4]; acc1.y += al * (float)u[5];
            acc1.z += al * (float)u[6]; acc1.w += al * (float)u[7];
        }
    }
    const float4* bp = reinterpret_cast<const float4*>(&bias[f0]);
    float4 b0 = bp[0], b1 = bp[1];
    float4 o0 = make_float4(elu(acc0.x + b0.x), elu(acc0.y + b0.y),
                            elu(acc0.z + b0.z), elu(acc0.w + b0.w));
    float4 o1 = make_float4(elu(acc1.x + b1.x), elu(acc1.y + b1.y),
                            elu(acc1.z + b1.z), elu(acc1.w + b1.w));
    float4* op = reinterpret_cast<float4*>(&out[(size_t)node * FDIM + f0]);
    op[0] = o0; op[1] = o1;
    // fused TopK pool score
    const float4* wp = reinterpret_cast<const float4*>(&pw[f0]);
    float4 w0 = wp[0], w1 = wp[1];
    float s = o0.x * w0.x + o0.y * w0.y + o0.z * w0.z + o0.w * w0.w
            + o1.x * w1.x + o1.y * w1.y + o1.z * w1.z + o1.w * w1.w;
#pragma unroll
    for (int off = 32; off > 0; off >>= 1) s += __shfl_xor(s, off);
    if (lane == 0) score[node] = tanhf(s * (*invn));
}

// ---- exact top-k select (4x 8-bit radix) + compact, single block -----------
// r5: threshold scan parallelized (suffix-scan over 256 buckets); verified.
// r8: zbuf/zn zero the padded readout accumulators (acc[10*32]) for the
// dot-first final_reduce; w/invn compute 1/||w|| when w non-null.
__global__ __launch_bounds__(1024) void select_compact(const float* __restrict__ score,
        int n, int k, int* __restrict__ remap, int* __restrict__ oldidx,
        float* __restrict__ zbuf, int zn,
        const float* __restrict__ w, float* __restrict__ invn)
{
    __shared__ unsigned hist[16][256];
    __shared__ unsigned wtot[4];
    __shared__ unsigned s_prefix, s_rem, l_tie, l_keep;
    __shared__ float red2[16];
    int t = threadIdx.x;
    int wv = t >> 6;
    unsigned keys[SELCAP];
#pragma unroll
    for (int j = 0; j < SELCAP; ++j){
        int i = t + j * 1024;
        keys[j] = (i < n) ? ordkey(score[i]) : 0u;
    }
    if (t == 0){ s_prefix = 0u; s_rem = (unsigned)k; l_tie = 0u; l_keep = 0u; }
    for (int i = t; i < 16 * 256; i += 1024) ((unsigned*)hist)[i] = 0u;
    if (zbuf && t < zn) zbuf[t] = 0.f;
    __syncthreads();
    for (int pass = 3; pass >= 0; --pass){
        unsigned shift = (unsigned)pass * 8u;
        unsigned pmask = (pass == 3) ? 0u : (0xFFFFFFFFu << (shift + 8u));
        unsigned pref = s_prefix;
        unsigned remv = s_rem;           // all threads read before any write
#pragma unroll
        for (int j = 0; j < SELCAP; ++j){
            int i = t + j * 1024;
            if (i < n && (keys[j] & pmask) == pref)
                atomicAdd(&hist[wv][(keys[j] >> shift) & 255u], 1u);
        }
        __syncthreads();
        unsigned c = 0, v = 0;
        if (t < 256){
            unsigned a = 0;
#pragma unroll
            for (int wq = 0; wq < 16; ++wq) a += hist[wq][t];
            c = a; v = a;
            // inclusive suffix scan within this wave's 64-bucket chunk
#pragma unroll
            for (int off = 1; off < 64; off <<= 1){
                unsigned o = __shfl_down(v, off);
                if ((t & 63) + off < 64) v += o;
            }
            if ((t & 63) == 0) wtot[t >> 6] = v;   // chunk total (lane 0 = full suffix of chunk)
        }
        __syncthreads();
        if (t < 256){
#pragma unroll
            for (int q = 0; q < 4; ++q)
                if (q > (t >> 6)) v += wtot[q];    // add totals of higher chunks
            unsigned nxt = v - c;                   // suffix(t+1)
            if (v >= remv && nxt < remv){           // unique: suffix monotone
                s_prefix = pref | ((unsigned)t << shift);
                s_rem = remv - nxt;
            }
        }
        __syncthreads();
        if (pass > 0){
            for (int i = t; i < 16 * 256; i += 1024) ((unsigned*)hist)[i] = 0u;
            __syncthreads();
        }
    }
    unsigned T = s_prefix, ties = s_rem;
#pragma unroll
    for (int j = 0; j < SELCAP; ++j){
        int i = t + j * 1024;
        if (i >= n) continue;
        unsigned key = keys[j];
        int keep = 0;
        if (key > T) keep = 1;
        else if (key == T){
            unsigned tk = atomicAdd(&l_tie, 1u);
            if (tk < ties) keep = 1;
        }
        if (keep){
            int pos = (int)atomicAdd(&l_keep, 1u);
            remap[i] = pos;
            oldidx[pos] = i;
        } else remap[i] = -1;
    }
    if (w){
        float s = (t < 512) ? w[t] * w[t] : 0.f;
#pragma unroll
        for (int off = 32; off > 0; off >>= 1) s += __shfl_xor(s, off);
        if ((t & 63) == 0) red2[wv] = s;
        __syncthreads();
        if (t == 0){
            float a = 0.f;
            for (int i = 0; i < 16; ++i) a += red2[i];
            *invn = rsqrtf(a);
        }
    }
}

// --------- readout: dot-first mean-pool + final 512x10 GEMM ----------------
// r8: REWRITE #3. r5 gather-chain 48us; r6 same-line atomics 70us; r7
// single-block 512KB atomic-load tail 48us. Lesson: any single-block tail
// >100KB or >500 same-line RMWs is a double-digit-us serializer. Now each
// block dots its partial sum with Wl LOCALLY (10 outputs) and atomicAdds
// into acc[w*32] — 10 line-padded accumulators, 250 RMWs each (~2us,
// parallel across lines). No done counter, no tail. final_out adds bias.
__global__ __launch_bounds__(512) void final_reduce(const float* __restrict__ x,
        const int* __restrict__ remap, const float* __restrict__ score,
        float* __restrict__ acc, const float* __restrict__ Wl)
{
    __shared__ float gsh[512];
    int t = threadIdx.x; // 512
    int r0 = blockIdx.x * FR_RPB;
    float a = 0.f;
#pragma unroll
    for (int i = 0; i < FR_RPB; i += 4){
        int rr = r0 + i;
        float s0 = (remap[rr + 0] >= 0) ? score[rr + 0] : 0.f;
        float s1 = (remap[rr + 1] >= 0) ? score[rr + 1] : 0.f;
        float s2 = (remap[rr + 2] >= 0) ? score[rr + 2] : 0.f;
        float s3 = (remap[rr + 3] >= 0) ? score[rr + 3] : 0.f;
        float v0 = x[(size_t)(rr + 0) * FDIM + t];
        float v1 = x[(size_t)(rr + 1) * FDIM + t];
        float v2 = x[(size_t)(rr + 2) * FDIM + t];
        float v3 = x[(size_t)(rr + 3) * FDIM + t];
        a += v0 * s0 + v1 * s1 + v2 * s2 + v3 * s3;
    }
    gsh[t] = a;
    __syncthreads();
    int wv = t >> 6, lane = t & 63;
#pragma unroll
    for (int rep = 0; rep < 2; ++rep){
        int w = wv + rep * 8;
        if (w >= 10) break;
        float s = 0.f;
#pragma unroll
        for (int f = 0; f < 8; ++f) s += gsh[lane + f * 64] * Wl[(lane + f * 64) * 10 + w];
#pragma unroll
        for (int off = 32; off > 0; off >>= 1) s += __shfl_xor(s, off);
        if (lane == 0) atomicAdd(&acc[w * 32], s);
    }
}

// tiny epilogue: out[w] = acc[w*32]/K2 + bl[w]
__global__ __launch_bounds__(64) void final_out(const float* __restrict__ acc,
        const float* __restrict__ bl, float* __restrict__ out)
{
    int t = threadIdx.x;
    if (t < 10) out[t] = acc[t * 32] * (1.0f / K2_KEEP) + bl[t];
}

extern "C" void kernel_launch(void* const* d_in, const int* in_sizes, int n_in,
                              void* d_out, int out_size, void* d_ws, size_t ws_size,
                              hipStream_t stream)
{
    (void)in_sizes; (void)n_in; (void)out_size; (void)ws_size;
    const float* x   = (const float*)d_in[0];
    const int*   ei  = (const int*)  d_in[1];
    const float* W1  = (const float*)d_in[3];
    const float* as1 = (const float*)d_in[4];
    const float* ad1 = (const float*)d_in[5];
    const float* b1  = (const float*)d_in[6];
    const float* pw1 = (const float*)d_in[7];
    const float* W2  = (const float*)d_in[8];
    const float* as2 = (const float*)d_in[9];
    const float* ad2 = (const float*)d_in[10];
    const float* b2  = (const float*)d_in[11];
    const float* pw2 = (const float*)d_in[12];
    const float* Wl  = (const float*)d_in[13];
    const float* bl  = (const float*)d_in[14];
    const int* src1 = ei;
    const int* dst1 = ei + E_EDGES;

    char* wsb = (char*)d_ws;
    size_t off = 0;
    auto alloc = [&](size_t bytes) -> char* {
        char* p = wsb + off;
        off += (bytes + 255) & ~(size_t)255;
        return p;
    };
    _Float16* h1f = (_Float16*)alloc((size_t)N_NODES * FDIM * 2); // fp16 gather rows (L1; L2 aliases)
    float* out1 = (float*)alloc((size_t)N_NODES * FDIM * 4);      // L1 GAT out; out2 aliases
    float* asrc = (float*)alloc((size_t)N_NODES * NHEAD * 4);     // L2: asrcH[K1][4][2]
    float* adst = (float*)alloc((size_t)N_NODES * NHEAD * 4);     // L2: adstH[K1][4][2]
    float* score= (float*)alloc((size_t)N_NODES * 4);
    float* invn = (float*)alloc(4);
    int* tmp  = (int*)alloc((size_t)N_NODES * 4);
    int* csr  = (int*)alloc((size_t)N_NODES * BSTRIDE * 4);
    int* remap= (int*)alloc((size_t)N_NODES * 4);
    int* oldi = (int*)alloc((size_t)K1_KEEP * 4);
    float* racc = (float*)alloc(320 * 4);                        // 10 line-padded accumulators
    _Float16* a0p = (_Float16*)alloc((size_t)MPAD * FDIM * 2);  // fp16 hi plane
    _Float16* a1p = (_Float16*)alloc((size_t)MPAD * FDIM * 2);  // fp16 lo plane
    _Float16* w2t0 = (_Float16*)alloc((size_t)FDIM * FDIM * 2); // W2^T hi
    _Float16* w2t1 = (_Float16*)alloc((size_t)FDIM * FDIM * 2); // W2^T lo
    _Float16* h2f = h1f;   // L2 gather rows alias L1's (L1 reads done by then)
    float* out2 = out1;    // L2 GAT out aliases out1 (out1 reads done by then)

    // ---- layer 1 (GAT on N nodes, E edges + self loops) ----
    int gx1 = (N_NODES + 63) / 64;
    int ngemm1 = gx1 * 4;
    int nclr = (N_NODES + 255) / 256;
    gemm_tile<64, 128, 1, false, true><<<ngemm1 + nclr, 256, 0, stream>>>(x, W1, h1f,
            nullptr, nullptr, as1, ad1, asrc, adst, N_NODES,
            ngemm1, tmp, N_NODES, pw1, invn);
    prep_w2<<<256, 256, 0, stream>>>(W2, w2t0, w2t1);   // no deps; done early
    edge_fill<<<(E_EDGES + 255) / 256, 256, 0, stream>>>(src1, dst1, E_EDGES, tmp, csr);
    gat_fused<false><<<(N_NODES + 3) / 4, 256, 0, stream>>>(h1f, asrc, adst, tmp, csr,
            nullptr, nullptr, b1, pw1, invn, out1, score, N_NODES);

    // ---- pool 1; also preps pw2-norm for layer-2 pool ----
    select_compact<<<1, 1024, 0, stream>>>(score, N_NODES, K1_KEEP, remap, oldi,
                                           nullptr, 0, pw2, invn);

    // ---- layer 2: gather+scale+split A, then fp16x2 MFMA GEMM ----
    prep_a<<<MPAD / 4, 256, 0, stream>>>(out1, oldi, score, a0p, a1p);
    gemm2_mfma<<<(MPAD / 128) * 4, 256, 0, stream>>>(a0p, a1p, w2t0, w2t1,
            as2, ad2, h2f, asrc, adst);
    gat_fused<true><<<(K1_KEEP + 3) / 4, 256, 0, stream>>>(h2f, asrc, adst, tmp, csr,
            oldi, remap, b2, pw2, invn, out2, score, K1_KEEP);

    // ---- pool 2 (zeroes racc) + dot-first readout ----
    select_compact<<<1, 1024, 0, stream>>>(score, K1_KEEP, K2_KEEP, remap, oldi,
                                           racc, 320, nullptr, nullptr);
    final_reduce<<<FR_GRID, 512, 0, stream>>>(out2, remap, score, racc, Wl);
    final_out<<<1, 64, 0, stream>>>(racc, bl, (float*)d_out);
}

// Round 9
// 271.047 us; speedup vs baseline: 1.2187x; 1.0117x over previous
//
#include <hip/hip_runtime.h>
#include <math.h>

#define N_NODES 20000
#define E_EDGES 200000
#define K1_KEEP 10000
#define K2_KEEP 5000
#define HIDC 128
#define NHEAD 4
#define FDIM 512   // NHEAD*HIDC
#define NEG 0.2f
#define BSTRIDE 64 // bucket CSR stride; P(deg>64)~e^-64 for Binom(200k,1/20k)
#define SELCAP 20  // keys/thread in select (1024*20 >= 20000)
#define MPAD 10112  // 79*128: K1 rows padded to GEMM2 tile grid
#define MPAD1 20096 // 157*128: N rows padded to GEMM1 tile grid
#define FR_GRID 250 // final_reduce blocks: 250*40 == K1_KEEP
#define FR_RPB 40   // rows per block (contiguous stream)

typedef _Float16 half8 __attribute__((ext_vector_type(8)));
typedef _Float16 half4 __attribute__((ext_vector_type(4)));
typedef float f32x4 __attribute__((ext_vector_type(4)));

__device__ __forceinline__ float leaky(float x){ return x > 0.f ? x : NEG * x; }
__device__ __forceinline__ float elu(float x){ return x > 0.f ? x : expm1f(x); }
// monotone float->uint key (ascending)
__device__ __forceinline__ unsigned ordkey(float f){
    unsigned u = __float_as_uint(f);
    return (u & 0x80000000u) ? ~u : (u | 0x80000000u);
}

// --------- prep: split x[N][64] fp32 -> X0,X1 fp16 planes [MPAD1][64] ------
// r9: L1 GEMM moves to MFMA; hi/lo split gives ~fp32 precision (22 mant bits).
__global__ __launch_bounds__(256) void prep_x(const float* __restrict__ x,
        _Float16* __restrict__ X0, _Float16* __restrict__ X1)
{
    int tid = blockIdx.x * 256 + threadIdx.x;   // MPAD1*8 total
    int r = tid >> 3, c8 = (tid & 7) << 3;
    half8 v0 = (half8)0, v1 = (half8)0;
    if (r < N_NODES){
        const float4* p = reinterpret_cast<const float4*>(&x[(size_t)r * 64 + c8]);
        float4 x0 = p[0], x1 = p[1];
        float vals[8] = {x0.x, x0.y, x0.z, x0.w, x1.x, x1.y, x1.z, x1.w};
#pragma unroll
        for (int j = 0; j < 8; ++j){
            _Float16 h = (_Float16)vals[j];
            v0[j] = h;
            v1[j] = (_Float16)(vals[j] - (float)h);
        }
    }
    *reinterpret_cast<half8*>(&X0[(size_t)r * 64 + c8]) = v0;
    *reinterpret_cast<half8*>(&X1[(size_t)r * 64 + c8]) = v1;
}

// --------- prep: W1 transpose-split + tmp zero + 1/||pw1|| (old CLEAR) -----
__global__ __launch_bounds__(256) void prep_w1x(const float* __restrict__ W1,
        _Float16* __restrict__ B0, _Float16* __restrict__ B1,
        int* __restrict__ ctmp, int cn,
        const float* __restrict__ cw, float* __restrict__ cinvn)
{
    int bid = blockIdx.x;
    int t = threadIdx.x;
    if (bid < 32){
        __shared__ float tile[32][33];
        int bn = bid & 15, bk = bid >> 4;   // W1 is [64][512]
        int n0 = bn * 32, k0 = bk * 32;
        int j = t & 31, i0 = t >> 5;
#pragma unroll
        for (int ii = 0; ii < 32; ii += 8)
            tile[i0 + ii][j] = W1[(size_t)(k0 + i0 + ii) * 512 + n0 + j];
        __syncthreads();
#pragma unroll
        for (int ii = 0; ii < 32; ii += 8){
            float v = tile[j][i0 + ii];     // = W1[k0+j][n0+i0+ii]
            _Float16 h0 = (_Float16)v;
            _Float16 h1 = (_Float16)(v - (float)h0);
            size_t o = (size_t)(n0 + i0 + ii) * 64 + k0 + j;
            B0[o] = h0; B1[o] = h1;
        }
    } else if (bid < 32 + 79){
        int i = (bid - 32) * 256 + t;
        if (i < cn) ctmp[i] = 0;
    } else {
        __shared__ float redc[4];
        float s = cw[t] * cw[t] + cw[t + 256] * cw[t + 256];
#pragma unroll
        for (int off = 32; off > 0; off >>= 1) s += __shfl_xor(s, off);
        if ((t & 63) == 0) redc[t >> 6] = s;
        __syncthreads();
        if (t == 0) *cinvn = rsqrtf(redc[0] + redc[1] + redc[2] + redc[3]);
    }
}

// --------- prep: transpose + fp16x2-split W2 -> W2T planes [n][k] ----------
__global__ __launch_bounds__(256) void prep_w2(const float* __restrict__ W2,
        _Float16* __restrict__ B0, _Float16* __restrict__ B1)
{
    __shared__ float tile[32][33];
    int bn = blockIdx.x & 15, bk = blockIdx.x >> 4;
    int n0 = bn * 32, k0 = bk * 32;
    int t = threadIdx.x;
    int j = t & 31, i0 = t >> 5;           // 8 row-groups of 32 cols
#pragma unroll
    for (int ii = 0; ii < 32; ii += 8)
        tile[i0 + ii][j] = W2[(size_t)(k0 + i0 + ii) * 512 + n0 + j];
    __syncthreads();
#pragma unroll
    for (int ii = 0; ii < 32; ii += 8){
        float v = tile[j][i0 + ii];        // = W2[k0+j][n0+i0+ii]
        _Float16 h0 = (_Float16)v;
        _Float16 h1 = (_Float16)(v - (float)h0);
        size_t o = (size_t)(n0 + i0 + ii) * 512 + k0 + j;
        B0[o] = h0; B1[o] = h1;
    }
}

// --------- prep: gather+scale+fp16x2-split A -> A planes [MPAD][512] -------
__global__ __launch_bounds__(256) void prep_a(const float* __restrict__ out1,
        const int* __restrict__ oldi, const float* __restrict__ score,
        _Float16* __restrict__ A0, _Float16* __restrict__ A1)
{
    int tid = blockIdx.x * 256 + threadIdx.x;   // MPAD*64 total
    int r = tid >> 6, kq = (tid & 63) << 3;
    half8 v0 = (half8)0, v1 = (half8)0;
    if (r < K1_KEEP){
        int o = oldi[r];
        float sc = score[o];
        const float4* p = reinterpret_cast<const float4*>(&out1[(size_t)o * 512 + kq]);
        float4 x0 = p[0], x1 = p[1];
        float vals[8] = {x0.x, x0.y, x0.z, x0.w, x1.x, x1.y, x1.z, x1.w};
#pragma unroll
        for (int j = 0; j < 8; ++j){
            float v = vals[j] * sc;
            _Float16 h = (_Float16)v;
            v0[j] = h;
            v1[j] = (_Float16)(v - (float)h);
        }
    }
    *reinterpret_cast<half8*>(&A0[(size_t)r * 512 + kq]) = v0;
    *reinterpret_cast<half8*>(&A1[(size_t)r * 512 + kq]) = v1;
}

// ---------------- GEMM: fp16x2 split MFMA, 128x128 tile, templated K -------
// C[nrows x 512] = A@B^T via 3 products A0B0+A0B1+A1B0 in fp32 MFMA acc
// (~fp32 precision). r2-verified structure (KK=512); r9 generalizes row
// stride/chunk count so KK=64 serves layer 1 (2 chunks, same dbuf loop).
// Epilogue: C fp16 + attention half-dot pairs [n][4][2] (head = bidn).
template<int KK>
__global__ __launch_bounds__(256, 2) void gemm_mfma(
        const _Float16* __restrict__ A0, const _Float16* __restrict__ A1,
        const _Float16* __restrict__ B0, const _Float16* __restrict__ B1,
        const float* __restrict__ avS, const float* __restrict__ avD,
        _Float16* __restrict__ C, float* __restrict__ asrc, float* __restrict__ adst,
        int nrows)
{
    __shared__ _Float16 smem[2][4][128][32];   // 65536 B
    int t = threadIdx.x;
    int l = t & 63, w = t >> 6;
    int wr = w >> 1, wc = w & 1;
    int bidn = blockIdx.x & 3, bidm = blockIdx.x >> 2;
    int row0 = bidm * 128, col0 = bidn * 128;

    // wave w stages plane w: 0->A0 1->A1 2->B0 3->B1
    const _Float16* plane = (w == 0) ? A0 : (w == 1) ? A1 : (w == 2) ? B0 : B1;
    int prow0 = (w < 2) ? row0 : col0;
    int mloc = l >> 2;                        // row within 16-row stripe
    int gsw = (l & 3) ^ (mloc & 3);           // inverse-swizzled src granule
    const _Float16* gbase = plane + (size_t)(prow0 + mloc) * KK + gsw * 8;

    f32x4 acc[4][4];
#pragma unroll
    for (int m = 0; m < 4; ++m)
#pragma unroll
        for (int n = 0; n < 4; ++n) acc[m][n] = (f32x4){0.f, 0.f, 0.f, 0.f};

    auto stage = [&](int buf, int chunk){
        const _Float16* src = gbase + chunk * 32;
        char* db = (char*)&smem[buf][w][0][0];
#pragma unroll
        for (int i = 0; i < 8; ++i)
            __builtin_amdgcn_global_load_lds(
                (const __attribute__((address_space(1))) void*)(src + (size_t)i * (KK * 16)),
                (__attribute__((address_space(3))) void*)(db + i * 1024), 16, 0, 0);
    };

    // frag read: row = l&15, k-granule = (l>>4) ^ swizzle(row&3) = (l>>4)^(l&3)
    int rb = (l & 15) * 64 + (((l >> 4) ^ (l & 3)) * 16);
    const char* sb = (const char*)smem;

    constexpr int NCH = KK / 32;
    stage(0, 0);
    __syncthreads();
    for (int c = 0; c < NCH; ++c){
        int buf = c & 1;
        if (c < NCH - 1) stage(buf ^ 1, c + 1);
        const char* base = sb + buf * 32768;
        half8 a0[4], a1[4], b0[4], b1[4];
#pragma unroll
        for (int m = 0; m < 4; ++m){
            a0[m] = *(const half8*)(base +         wr * 4096 + m * 1024 + rb);
            a1[m] = *(const half8*)(base +  8192 + wr * 4096 + m * 1024 + rb);
            b0[m] = *(const half8*)(base + 16384 + wc * 4096 + m * 1024 + rb);
            b1[m] = *(const half8*)(base + 24576 + wc * 4096 + m * 1024 + rb);
        }
        // product-major order: each acc reused every 16 MFMAs (no RAW stall)
#pragma unroll
        for (int m = 0; m < 4; ++m)
#pragma unroll
            for (int n = 0; n < 4; ++n)
                acc[m][n] = __builtin_amdgcn_mfma_f32_16x16x32_f16(a0[m], b0[n], acc[m][n], 0, 0, 0);
#pragma unroll
        for (int m = 0; m < 4; ++m)
#pragma unroll
            for (int n = 0; n < 4; ++n)
                acc[m][n] = __builtin_amdgcn_mfma_f32_16x16x32_f16(a0[m], b1[n], acc[m][n], 0, 0, 0);
#pragma unroll
        for (int m = 0; m < 4; ++m)
#pragma unroll
            for (int n = 0; n < 4; ++n)
                acc[m][n] = __builtin_amdgcn_mfma_f32_16x16x32_f16(a1[m], b0[n], acc[m][n], 0, 0, 0);
        __syncthreads();
    }

    // epilogue: C/D frag layout col=lane&15, row=(lane>>4)*4+reg (m89)
    int head = bidn;
    const float* asv = avS + head * HIDC + wc * 64;
    const float* adv = avD + head * HIDC + wc * 64;
    int lc = l & 15, lg = l >> 4;
    int rbase = row0 + wr * 64;
    int cbase = col0 + wc * 64;
#pragma unroll
    for (int m = 0; m < 4; ++m){
#pragma unroll
        for (int q = 0; q < 4; ++q){
            int row = rbase + m * 16 + lg * 4 + q;
            bool ok = row < nrows;
            float s = 0.f, d = 0.f;
#pragma unroll
            for (int n = 0; n < 4; ++n){
                float v = acc[m][n][q];
                int cc = n * 16 + lc;
                if (ok) C[(size_t)row * 512 + cbase + cc] = (_Float16)v;
                s += v * asv[cc];
                d += v * adv[cc];
            }
#pragma unroll
            for (int off = 1; off < 16; off <<= 1){
                s += __shfl_xor(s, off);
                d += __shfl_xor(d, off);
            }
            if (ok && lc == 0){
                asrc[row * 8 + head * 2 + wc] = s;   // half-pair layout [n][4][2]
                adst[row * 8 + head * 2 + wc] = d;
            }
        }
    }
}

// bucketed CSR fill: no count/scan passes needed; tmp returns degrees.
__global__ void edge_fill(const int* __restrict__ src, const int* __restrict__ dst, int e,
                          int* __restrict__ tmp, int* __restrict__ csr){
    int i = blockIdx.x * 256 + threadIdx.x;
    if (i >= e) return;
    int d = dst[i];
    int pos = atomicAdd(&tmp[d], 1);
    if (pos < BSTRIDE) csr[d * BSTRIDE + pos] = src[i];
}

// ---- fused softmax-stats + aggregation + pool score, one wave per node -----
// r4: h rows fp16 (16B/lane/edge) — gather service-rate-bound, bytes halved.
// r9: both layers now use the [n][4][2] half-pair attention layout (gemm_mfma
// epilogue); FILTER only controls remap/oldi indirection.
template<bool FILTER>
__global__ __launch_bounds__(256) void gat_fused(const _Float16* __restrict__ h,
        const float* __restrict__ asrc, const float* __restrict__ adst,
        const int* __restrict__ degs, const int* __restrict__ csr,
        const int* __restrict__ oldi, const int* __restrict__ remap,
        const float* __restrict__ bias, const float* __restrict__ pw,
        const float* __restrict__ invn, float* __restrict__ out,
        float* __restrict__ score, int n)
{
    int node = blockIdx.x * 4 + (threadIdx.x >> 6);
    int lane = threadIdx.x & 63;
    if (node >= n) return;
    int od = FILTER ? oldi[node] : node;
    int deg = degs[od]; if (deg > BSTRIDE) deg = BSTRIDE;
    int e0 = od * BSTRIDE;
    int ph = lane & 3;
    int pe = lane >> 2;
    float adn, sown;
    {
        float2 dv = *reinterpret_cast<const float2*>(&adst[(size_t)node * 8 + ph * 2]);
        float2 sv = *reinterpret_cast<const float2*>(&asrc[(size_t)node * 8 + ph * 2]);
        adn = dv.x + dv.y; sown = sv.x + sv.y;
    }
    float slog = leaky(sown + adn);
    int sreg[4];
    float mx = slog;
#pragma unroll
    for (int blk = 0; blk < 4; ++blk){
        int j = blk * 16 + pe;
        int s = -1;
        if (j < deg){
            s = csr[e0 + j];
            if (FILTER) s = remap[s];
            if (s >= 0){
                float2 v = *reinterpret_cast<const float2*>(&asrc[(size_t)s * 8 + ph * 2]);
                mx = fmaxf(mx, leaky(v.x + v.y + adn));
            }
        }
        sreg[blk] = s;
    }
#pragma unroll
    for (int off = 4; off < 64; off <<= 1) mx = fmaxf(mx, __shfl_xor(mx, off));
    float aexp[4];
    float lsum = 0.f;
#pragma unroll
    for (int blk = 0; blk < 4; ++blk){
        float ex = 0.f;
        int s = sreg[blk];
        if (s >= 0){
            float2 v = *reinterpret_cast<const float2*>(&asrc[(size_t)s * 8 + ph * 2]);
            ex = expf(leaky(v.x + v.y + adn) - mx);
        }
        aexp[blk] = ex;
        lsum += ex;
    }
#pragma unroll
    for (int off = 4; off < 64; off <<= 1) lsum += __shfl_xor(lsum, off);
    float es  = expf(slog - mx);
    float inv = 1.f / (lsum + es);

    int f0 = lane * 8;
    int hf = lane >> 4;
    float invh  = __shfl(inv, hf);       // lane hf holds head hf's stats
    float aself = __shfl(es, hf) * invh;
    float4 acc0, acc1;
    {
        half8 v = *reinterpret_cast<const half8*>(&h[(size_t)node * FDIM + f0]);
        acc0 = make_float4(aself * (float)v[0], aself * (float)v[1],
                           aself * (float)v[2], aself * (float)v[3]);
        acc1 = make_float4(aself * (float)v[4], aself * (float)v[5],
                           aself * (float)v[6], aself * (float)v[7]);
    }
#pragma unroll
    for (int blk = 0; blk < 4; ++blk){
        int base = blk * 16;
        if (base >= deg) break;
        int cnt = deg - base; if (cnt > 16) cnt = 16;
        for (int e = 0; e < cnt; ++e){
            int s = __shfl(sreg[blk], e * 4);
            if (FILTER && s < 0) continue;
            float al = __shfl(aexp[blk], e * 4 + hf) * invh;
            half8 u = *reinterpret_cast<const half8*>(&h[(size_t)s * FDIM + f0]);
            acc0.x += al * (float)u[0]; acc0.y += al * (float)u[1];
            acc0.z += al * (float)u[2]; acc0.w += al * (float)u[3];
            acc1.x += al * (float)u[4]; acc1.y += al * (float)u[5];
            acc1.z += al * (float)u[6]; acc1.w += al * (float)u[7];
        }
    }
    const float4* bp = reinterpret_cast<const float4*>(&bias[f0]);
    float4 b0 = bp[0], b1 = bp[1];
    float4 o0 = make_float4(elu(acc0.x + b0.x), elu(acc0.y + b0.y),
                            elu(acc0.z + b0.z), elu(acc0.w + b0.w));
    float4 o1 = make_float4(elu(acc1.x + b1.x), elu(acc1.y + b1.y),
                            elu(acc1.z + b1.z), elu(acc1.w + b1.w));
    float4* op = reinterpret_cast<float4*>(&out[(size_t)node * FDIM + f0]);
    op[0] = o0; op[1] = o1;
    // fused TopK pool score
    const float4* wp = reinterpret_cast<const float4*>(&pw[f0]);
    float4 w0 = wp[0], w1 = wp[1];
    float s = o0.x * w0.x + o0.y * w0.y + o0.z * w0.z + o0.w * w0.w
            + o1.x * w1.x + o1.y * w1.y + o1.z * w1.z + o1.w * w1.w;
#pragma unroll
    for (int off = 32; off > 0; off >>= 1) s += __shfl_xor(s, off);
    if (lane == 0) score[node] = tanhf(s * (*invn));
}

// ---- exact top-k select (4x 8-bit radix) + compact, single block -----------
// r5: threshold scan parallelized (suffix-scan over 256 buckets); verified.
// r8: zbuf/zn zero the padded readout accumulators; w/invn compute 1/||w||.
__global__ __launch_bounds__(1024) void select_compact(const float* __restrict__ score,
        int n, int k, int* __restrict__ remap, int* __restrict__ oldidx,
        float* __restrict__ zbuf, int zn,
        const float* __restrict__ w, float* __restrict__ invn)
{
    __shared__ unsigned hist[16][256];
    __shared__ unsigned wtot[4];
    __shared__ unsigned s_prefix, s_rem, l_tie, l_keep;
    __shared__ float red2[16];
    int t = threadIdx.x;
    int wv = t >> 6;
    unsigned keys[SELCAP];
#pragma unroll
    for (int j = 0; j < SELCAP; ++j){
        int i = t + j * 1024;
        keys[j] = (i < n) ? ordkey(score[i]) : 0u;
    }
    if (t == 0){ s_prefix = 0u; s_rem = (unsigned)k; l_tie = 0u; l_keep = 0u; }
    for (int i = t; i < 16 * 256; i += 1024) ((unsigned*)hist)[i] = 0u;
    if (zbuf && t < zn) zbuf[t] = 0.f;
    __syncthreads();
    for (int pass = 3; pass >= 0; --pass){
        unsigned shift = (unsigned)pass * 8u;
        unsigned pmask = (pass == 3) ? 0u : (0xFFFFFFFFu << (shift + 8u));
        unsigned pref = s_prefix;
        unsigned remv = s_rem;           // all threads read before any write
#pragma unroll
        for (int j = 0; j < SELCAP; ++j){
            int i = t + j * 1024;
            if (i < n && (keys[j] & pmask) == pref)
                atomicAdd(&hist[wv][(keys[j] >> shift) & 255u], 1u);
        }
        __syncthreads();
        unsigned c = 0, v = 0;
        if (t < 256){
            unsigned a = 0;
#pragma unroll
            for (int wq = 0; wq < 16; ++wq) a += hist[wq][t];
            c = a; v = a;
            // inclusive suffix scan within this wave's 64-bucket chunk
#pragma unroll
            for (int off = 1; off < 64; off <<= 1){
                unsigned o = __shfl_down(v, off);
                if ((t & 63) + off < 64) v += o;
            }
            if ((t & 63) == 0) wtot[t >> 6] = v;   // chunk total (lane 0 = full suffix of chunk)
        }
        __syncthreads();
        if (t < 256){
#pragma unroll
            for (int q = 0; q < 4; ++q)
                if (q > (t >> 6)) v += wtot[q];    // add totals of higher chunks
            unsigned nxt = v - c;                   // suffix(t+1)
            if (v >= remv && nxt < remv){           // unique: suffix monotone
                s_prefix = pref | ((unsigned)t << shift);
                s_rem = remv - nxt;
            }
        }
        __syncthreads();
        if (pass > 0){
            for (int i = t; i < 16 * 256; i += 1024) ((unsigned*)hist)[i] = 0u;
            __syncthreads();
        }
    }
    unsigned T = s_prefix, ties = s_rem;
#pragma unroll
    for (int j = 0; j < SELCAP; ++j){
        int i = t + j * 1024;
        if (i >= n) continue;
        unsigned key = keys[j];
        int keep = 0;
        if (key > T) keep = 1;
        else if (key == T){
            unsigned tk = atomicAdd(&l_tie, 1u);
            if (tk < ties) keep = 1;
        }
        if (keep){
            int pos = (int)atomicAdd(&l_keep, 1u);
            remap[i] = pos;
            oldidx[pos] = i;
        } else remap[i] = -1;
    }
    if (w){
        float s = (t < 512) ? w[t] * w[t] : 0.f;
#pragma unroll
        for (int off = 32; off > 0; off >>= 1) s += __shfl_xor(s, off);
        if ((t & 63) == 0) red2[wv] = s;
        __syncthreads();
        if (t == 0){
            float a = 0.f;
            for (int i = 0; i < 16; ++i) a += red2[i];
            *invn = rsqrtf(a);
        }
    }
}

// --------- readout: dot-first mean-pool + final 512x10 GEMM ----------------
// r8-verified: per-block local 10-dot + line-padded atomics (no tails).
__global__ __launch_bounds__(512) void final_reduce(const float* __restrict__ x,
        const int* __restrict__ remap, const float* __restrict__ score,
        float* __restrict__ acc, const float* __restrict__ Wl)
{
    __shared__ float gsh[512];
    int t = threadIdx.x; // 512
    int r0 = blockIdx.x * FR_RPB;
    float a = 0.f;
#pragma unroll
    for (int i = 0; i < FR_RPB; i += 4){
        int rr = r0 + i;
        float s0 = (remap[rr + 0] >= 0) ? score[rr + 0] : 0.f;
        float s1 = (remap[rr + 1] >= 0) ? score[rr + 1] : 0.f;
        float s2 = (remap[rr + 2] >= 0) ? score[rr + 2] : 0.f;
        float s3 = (remap[rr + 3] >= 0) ? score[rr + 3] : 0.f;
        float v0 = x[(size_t)(rr + 0) * FDIM + t];
        float v1 = x[(size_t)(rr + 1) * FDIM + t];
        float v2 = x[(size_t)(rr + 2) * FDIM + t];
        float v3 = x[(size_t)(rr + 3) * FDIM + t];
        a += v0 * s0 + v1 * s1 + v2 * s2 + v3 * s3;
    }
    gsh[t] = a;
    __syncthreads();
    int wv = t >> 6, lane = t & 63;
#pragma unroll
    for (int rep = 0; rep < 2; ++rep){
        int w = wv + rep * 8;
        if (w >= 10) break;
        float s = 0.f;
#pragma unroll
        for (int f = 0; f < 8; ++f) s += gsh[lane + f * 64] * Wl[(lane + f * 64) * 10 + w];
#pragma unroll
        for (int off = 32; off > 0; off >>= 1) s += __shfl_xor(s, off);
        if (lane == 0) atomicAdd(&acc[w * 32], s);
    }
}

// tiny epilogue: out[w] = acc[w*32]/K2 + bl[w]
__global__ __launch_bounds__(64) void final_out(const float* __restrict__ acc,
        const float* __restrict__ bl, float* __restrict__ out)
{
    int t = threadIdx.x;
    if (t < 10) out[t] = acc[t * 32] * (1.0f / K2_KEEP) + bl[t];
}

extern "C" void kernel_launch(void* const* d_in, const int* in_sizes, int n_in,
                              void* d_out, int out_size, void* d_ws, size_t ws_size,
                              hipStream_t stream)
{
    (void)in_sizes; (void)n_in; (void)out_size; (void)ws_size;
    const float* x   = (const float*)d_in[0];
    const int*   ei  = (const int*)  d_in[1];
    const float* W1  = (const float*)d_in[3];
    const float* as1 = (const float*)d_in[4];
    const float* ad1 = (const float*)d_in[5];
    const float* b1  = (const float*)d_in[6];
    const float* pw1 = (const float*)d_in[7];
    const float* W2  = (const float*)d_in[8];
    const float* as2 = (const float*)d_in[9];
    const float* ad2 = (const float*)d_in[10];
    const float* b2  = (const float*)d_in[11];
    const float* pw2 = (const float*)d_in[12];
    const float* Wl  = (const float*)d_in[13];
    const float* bl  = (const float*)d_in[14];
    const int* src1 = ei;
    const int* dst1 = ei + E_EDGES;

    char* wsb = (char*)d_ws;
    size_t off = 0;
    auto alloc = [&](size_t bytes) -> char* {
        char* p = wsb + off;
        off += (bytes + 255) & ~(size_t)255;
        return p;
    };
    _Float16* h1f = (_Float16*)alloc((size_t)N_NODES * FDIM * 2); // fp16 gather rows (L1; L2 aliases)
    float* out1 = (float*)alloc((size_t)N_NODES * FDIM * 4);      // L1 GAT out; out2 aliases
    float* asrc = (float*)alloc((size_t)N_NODES * 8 * 4);         // half-pair dots [n][4][2]
    float* adst = (float*)alloc((size_t)N_NODES * 8 * 4);
    float* score= (float*)alloc((size_t)N_NODES * 4);
    float* invn = (float*)alloc(4);
    int* tmp  = (int*)alloc((size_t)N_NODES * 4);
    int* csr  = (int*)alloc((size_t)N_NODES * BSTRIDE * 4);
    int* remap= (int*)alloc((size_t)N_NODES * 4);
    int* oldi = (int*)alloc((size_t)K1_KEEP * 4);
    float* racc = (float*)alloc(320 * 4);                        // 10 line-padded accumulators
    _Float16* a0p = (_Float16*)alloc((size_t)MPAD * FDIM * 2);  // L2 A hi plane
    _Float16* a1p = (_Float16*)alloc((size_t)MPAD * FDIM * 2);  // L2 A lo plane
    _Float16* w2t0 = (_Float16*)alloc((size_t)FDIM * FDIM * 2); // W2^T hi
    _Float16* w2t1 = (_Float16*)alloc((size_t)FDIM * FDIM * 2); // W2^T lo
    _Float16* x0p = (_Float16*)alloc((size_t)MPAD1 * 64 * 2);   // L1 A hi plane
    _Float16* x1p = (_Float16*)alloc((size_t)MPAD1 * 64 * 2);   // L1 A lo plane
    _Float16* w1t0 = (_Float16*)alloc((size_t)FDIM * 64 * 2);   // W1^T hi
    _Float16* w1t1 = (_Float16*)alloc((size_t)FDIM * 64 * 2);   // W1^T lo
    _Float16* h2f = h1f;   // L2 gather rows alias L1's (L1 reads done by then)
    float* out2 = out1;    // L2 GAT out aliases out1 (out1 reads done by then)

    // ---- layer 1 (GAT on N nodes, E edges + self loops), MFMA path ----
    prep_x<<<MPAD1 * 8 / 256, 256, 0, stream>>>(x, x0p, x1p);
    prep_w1x<<<112, 256, 0, stream>>>(W1, w1t0, w1t1, tmp, N_NODES, pw1, invn);
    gemm_mfma<64><<<(MPAD1 / 128) * 4, 256, 0, stream>>>(x0p, x1p, w1t0, w1t1,
            as1, ad1, h1f, asrc, adst, N_NODES);
    prep_w2<<<256, 256, 0, stream>>>(W2, w2t0, w2t1);   // no deps; done early
    edge_fill<<<(E_EDGES + 255) / 256, 256, 0, stream>>>(src1, dst1, E_EDGES, tmp, csr);
    gat_fused<false><<<(N_NODES + 3) / 4, 256, 0, stream>>>(h1f, asrc, adst, tmp, csr,
            nullptr, nullptr, b1, pw1, invn, out1, score, N_NODES);

    // ---- pool 1; also preps pw2-norm for layer-2 pool ----
    select_compact<<<1, 1024, 0, stream>>>(score, N_NODES, K1_KEEP, remap, oldi,
                                           nullptr, 0, pw2, invn);

    // ---- layer 2: gather+scale+split A, then fp16x2 MFMA GEMM ----
    prep_a<<<MPAD / 4, 256, 0, stream>>>(out1, oldi, score, a0p, a1p);
    gemm_mfma<512><<<(MPAD / 128) * 4, 256, 0, stream>>>(a0p, a1p, w2t0, w2t1,
            as2, ad2, h2f, asrc, adst, K1_KEEP);
    gat_fused<true><<<(K1_KEEP + 3) / 4, 256, 0, stream>>>(h2f, asrc, adst, tmp, csr,
            oldi, remap, b2, pw2, invn, out2, score, K1_KEEP);

    // ---- pool 2 (zeroes racc) + dot-first readout ----
    select_compact<<<1, 1024, 0, stream>>>(score, K1_KEEP, K2_KEEP, remap, oldi,
                                           racc, 320, nullptr, nullptr);
    final_reduce<<<FR_GRID, 512, 0, stream>>>(out2, remap, score, racc, Wl);
    final_out<<<1, 64, 0, stream>>>(racc, bl, (float*)d_out);
}